// Round 1
// baseline (1132.562 us; speedup 1.0000x reference)
//
#include <hip/hip_runtime.h>
#include <math.h>

#define DH 128      // HEADS*HID
#define HID_ 32
#define HEADS_ 4
#define EDIM_ 16
#define NG_ 64

__device__ __forceinline__ float lrelu(float v){ return v > 0.f ? v : 0.2f*v; }
__device__ __forceinline__ float elu_(float v){ return v > 0.f ? v : (expf(v)-1.f); }

// ---------------- CSR build ----------------
__global__ void k_hist(const int* __restrict__ dst, int E, int* __restrict__ counts){
    int e = blockIdx.x*blockDim.x + threadIdx.x;
    if (e < E) atomicAdd(&counts[dst[e]], 1);
}

__global__ void k_scan1(const int* __restrict__ counts, int N, int* __restrict__ rowst, int* __restrict__ bsums){
    __shared__ int s[512];
    int t = threadIdx.x; int i = blockIdx.x*512 + t;
    int v = (i < N) ? counts[i] : 0;
    s[t] = v; __syncthreads();
    for (int off = 1; off < 512; off <<= 1){
        int x = (t >= off) ? s[t-off] : 0;
        __syncthreads();
        s[t] += x;
        __syncthreads();
    }
    if (i < N) rowst[i] = s[t] - v;   // exclusive
    if (t == 511) bsums[blockIdx.x] = s[511];
}

__global__ void k_scan2(int* bsums, int nb){
    if (threadIdx.x == 0 && blockIdx.x == 0){
        int run = 0;
        for (int b = 0; b < nb; b++){ int v = bsums[b]; bsums[b] = run; run += v; }
    }
}

__global__ void k_scan3(int* rowst, const int* __restrict__ bsums, int N, int E){
    int i = blockIdx.x*blockDim.x + threadIdx.x;
    if (i < N) rowst[i] += bsums[i/512];
    if (i == 0) rowst[N] = E;
}

__global__ void k_scatter(const int* __restrict__ src, const int* __restrict__ dst, int E,
                          const int* __restrict__ rowst, int* __restrict__ cursor,
                          int* __restrict__ srcs, int* __restrict__ dsts, int* __restrict__ perm){
    int e = blockIdx.x*blockDim.x + threadIdx.x;
    if (e < E){
        int d = dst[e];
        int p = rowst[d] + atomicAdd(&cursor[d], 1);
        srcs[p] = src[e]; dsts[p] = d; perm[p] = e;
    }
}

// ---------------- small param precompute ----------------
__global__ void k_eamean(const float* __restrict__ ea, int E, float* __restrict__ colsum){
    int t = threadIdx.x; int col = t & 15; int rl = t >> 4;   // 16 rows x 16 cols
    float s = 0.f;
    for (long r = (long)blockIdx.x*16 + rl; r < E; r += (long)gridDim.x*16)
        s += ea[r*EDIM_ + col];
    __shared__ float sm[256];
    sm[t] = s; __syncthreads();
    for (int off = 128; off >= 16; off >>= 1){ if (t < off) sm[t] += sm[t+off]; __syncthreads(); }
    if (t < 16) atomicAdd(&colsum[t], sm[t]);
}

__global__ void k_ve(const float* __restrict__ We0, const float* __restrict__ ae0,
                     const float* __restrict__ We1, const float* __restrict__ ae1,
                     const float* __restrict__ We2, const float* __restrict__ ae2,
                     float* __restrict__ Ve){
    int idx = threadIdx.x;
    if (idx < 192){
        int l = idx/64, r = idx%64, k = r/4, h = r%4;
        const float* We = (l==0) ? We0 : (l==1) ? We1 : We2;
        const float* ae = (l==0) ? ae0 : (l==1) ? ae1 : ae2;
        float s = 0.f;
        for (int c = 0; c < HID_; c++) s += We[k*DH + h*HID_ + c] * ae[h*HID_ + c];
        Ve[idx] = s;
    }
}

__global__ void k_selfae(const float* __restrict__ colsum, const float* __restrict__ Ve,
                         float invE, float* __restrict__ selfae){
    int idx = threadIdx.x;
    if (idx < 12){
        int l = idx/4, h = idx%4; float s = 0.f;
        for (int k = 0; k < EDIM_; k++) s += colsum[k]*invE*Ve[l*64 + k*4 + h];
        selfae[idx] = s;
    }
}

// aedge in dst-sorted order, all 3 layers, one gather of edge_attr
__global__ void k_aedge(const float* __restrict__ ea, const int* __restrict__ perm, int E,
                        const float* __restrict__ Ve, float* __restrict__ aedge){
    __shared__ float vsm[192];
    if (threadIdx.x < 192) vsm[threadIdx.x] = Ve[threadIdx.x];
    __syncthreads();
    int i = blockIdx.x*blockDim.x + threadIdx.x;
    if (i >= E) return;
    int e = perm[i];
    const float4* p = (const float4*)(ea + (size_t)e*EDIM_);
    float v[16];
    #pragma unroll
    for (int q = 0; q < 4; q++){ float4 x = p[q]; v[q*4]=x.x; v[q*4+1]=x.y; v[q*4+2]=x.z; v[q*4+3]=x.w; }
    #pragma unroll
    for (int l = 0; l < 3; l++){
        float4 o; float* po = (float*)&o;
        #pragma unroll
        for (int h = 0; h < 4; h++){
            float s = 0.f;
            #pragma unroll
            for (int k = 0; k < EDIM_; k++) s += v[k]*vsm[l*64 + k*4 + h];
            po[h] = s;
        }
        *(float4*)(aedge + (size_t)i*12 + l*4) = o;
    }
}

// ---------------- per-layer kernels ----------------
// h = x @ W  (W: [K,128] row-major), fused a_src/a_dst epilogue
template<int K>
__global__ __launch_bounds__(256) void k_gemm(const float* __restrict__ x, const float* __restrict__ W,
                        const float* __restrict__ attS, const float* __restrict__ attD,
                        float* __restrict__ h, float* __restrict__ asrc, float* __restrict__ adst, int N){
    constexpr int KC = (K > 64) ? 64 : K;
    __shared__ float4 Ws[KC*32];      // [KC][128] floats
    __shared__ float  xs[8*K];
    int t = threadIdx.x;
    int nbase = blockIdx.x*8;
    const float4* Wg = (const float4*)W;
    // load 8 rows of x
    constexpr int XF4 = 8*K/4;
    const float4* xg = (const float4*)(x + (size_t)nbase*K);
    float4* xs4 = (float4*)xs;
    for (int i = t; i < XF4; i += 256){
        int row = i/(K/4);
        xs4[i] = (nbase + row < N) ? xg[i] : float4{0,0,0,0};
    }
    int r = t >> 5, cg = t & 31;
    float4 acc = {0,0,0,0};
    const float* xr = xs + r*K;
    for (int kc = 0; kc < K; kc += KC){
        for (int i = t; i < KC*32; i += 256) Ws[i] = Wg[kc*32 + i];
        __syncthreads();
        #pragma unroll 8
        for (int kk = 0; kk < KC; kk++){
            float xv = xr[kc + kk];
            float4 w = Ws[kk*32 + cg];
            acc.x += xv*w.x; acc.y += xv*w.y; acc.z += xv*w.z; acc.w += xv*w.w;
        }
        __syncthreads();
    }
    int n = nbase + r;
    if (n < N){
        *(float4*)(h + (size_t)n*DH + cg*4) = acc;
        int hd = cg >> 3, c0 = (cg & 7)*4;
        const float* as_ = attS + hd*HID_ + c0;
        const float* ad_ = attD + hd*HID_ + c0;
        float ps = acc.x*as_[0] + acc.y*as_[1] + acc.z*as_[2] + acc.w*as_[3];
        float pd = acc.x*ad_[0] + acc.y*ad_[1] + acc.z*ad_[2] + acc.w*ad_[3];
        ps += __shfl_xor(ps,1); ps += __shfl_xor(ps,2); ps += __shfl_xor(ps,4);
        pd += __shfl_xor(pd,1); pd += __shfl_xor(pd,2); pd += __shfl_xor(pd,4);
        if ((cg & 7) == 0){ asrc[n*4 + hd] = ps; adst[n*4 + hd] = pd; }
    }
}

// ex = exp(leakyrelu(asrc[src]+adst[dst]+aedge)) per sorted edge
__global__ void k_edge_ex(const int* __restrict__ srcs, const int* __restrict__ dsts, int E,
                          const float* __restrict__ asrc, const float* __restrict__ adst,
                          const float* __restrict__ aedge, int l,
                          const float* __restrict__ ea, const int* __restrict__ perm,
                          const float* __restrict__ Ve, float* __restrict__ exs){
    int i = blockIdx.x*blockDim.x + threadIdx.x;
    if (i >= E) return;
    int s = srcs[i], d = dsts[i];
    float4 av = *(const float4*)(asrc + (size_t)s*4);
    float4 dv = *(const float4*)(adst + (size_t)d*4);
    float4 ae4;
    if (aedge){
        ae4 = *(const float4*)(aedge + (size_t)i*12 + l*4);
    } else {
        int e = perm[i];
        const float4* p = (const float4*)(ea + (size_t)e*EDIM_);
        float v[16];
        #pragma unroll
        for (int q = 0; q < 4; q++){ float4 x = p[q]; v[q*4]=x.x; v[q*4+1]=x.y; v[q*4+2]=x.z; v[q*4+3]=x.w; }
        float o[4];
        #pragma unroll
        for (int h = 0; h < 4; h++){
            float su = 0.f;
            #pragma unroll
            for (int k = 0; k < EDIM_; k++) su += v[k]*Ve[l*64 + k*4 + h];
            o[h] = su;
        }
        ae4 = float4{o[0],o[1],o[2],o[3]};
    }
    float4 o;
    o.x = expf(lrelu(av.x + dv.x + ae4.x));
    o.y = expf(lrelu(av.y + dv.y + ae4.y));
    o.z = expf(lrelu(av.z + dv.z + ae4.z));
    o.w = expf(lrelu(av.w + dv.w + ae4.w));
    *(float4*)(exs + (size_t)i*4) = o;
}

// one wave per node: softmax denominator + weighted aggregation + bias (+head-mean)
template<int CONCAT>
__global__ __launch_bounds__(256) void k_agg(const int* __restrict__ rowst, const int* __restrict__ srcs,
                       const float* __restrict__ exs, const float* __restrict__ h,
                       const float* __restrict__ asrc, const float* __restrict__ adst,
                       const float* __restrict__ selfae, int l,
                       const float* __restrict__ bias, float* __restrict__ out, int N){
    int wv = threadIdx.x >> 6, lane = threadIdx.x & 63;
    int n = blockIdx.x*4 + wv;
    if (n >= N) return;
    int st = rowst[n], en = rowst[n+1];
    float4 dsum = {0,0,0,0};
    for (int i = st + lane; i < en; i += 64){
        float4 e4 = *(const float4*)(exs + (size_t)i*4);
        dsum.x += e4.x; dsum.y += e4.y; dsum.z += e4.z; dsum.w += e4.w;
    }
    #pragma unroll
    for (int m = 1; m < 64; m <<= 1){
        dsum.x += __shfl_xor(dsum.x, m);
        dsum.y += __shfl_xor(dsum.y, m);
        dsum.z += __shfl_xor(dsum.z, m);
        dsum.w += __shfl_xor(dsum.w, m);
    }
    float4 av = *(const float4*)(asrc + (size_t)n*4);
    float4 dv = *(const float4*)(adst + (size_t)n*4);
    float4 sa = *(const float4*)(selfae + l*4);
    float4 exself;
    exself.x = expf(lrelu(av.x + dv.x + sa.x));
    exself.y = expf(lrelu(av.y + dv.y + sa.y));
    exself.z = expf(lrelu(av.z + dv.z + sa.z));
    exself.w = expf(lrelu(av.w + dv.w + sa.w));
    float4 den = {dsum.x+exself.x, dsum.y+exself.y, dsum.z+exself.z, dsum.w+exself.w};
    int hd = lane >> 4;
    float dh  = hd==0 ? den.x    : hd==1 ? den.y    : hd==2 ? den.z    : den.w;
    float esh = hd==0 ? exself.x : hd==1 ? exself.y : hd==2 ? exself.z : exself.w;
    float invd = 1.f/dh;
    int f = lane*2;
    float2 acc = {0.f, 0.f};
    for (int i = st; i < en; i++){
        float4 e4 = *(const float4*)(exs + (size_t)i*4);
        float w = (hd==0 ? e4.x : hd==1 ? e4.y : hd==2 ? e4.z : e4.w)*invd;
        int s = srcs[i];
        float2 hv = *(const float2*)(h + (size_t)s*DH + f);
        acc.x += w*hv.x; acc.y += w*hv.y;
    }
    float2 hn = *(const float2*)(h + (size_t)n*DH + f);
    float wself = esh*invd;
    acc.x += wself*hn.x; acc.y += wself*hn.y;
    if (CONCAT){
        out[(size_t)n*DH + f]     = acc.x + bias[f];
        out[(size_t)n*DH + f + 1] = acc.y + bias[f+1];
    } else {
        acc.x += __shfl_xor(acc.x, 16); acc.y += __shfl_xor(acc.y, 16);
        acc.x += __shfl_xor(acc.x, 32); acc.y += __shfl_xor(acc.y, 32);
        if (lane < 16){
            int c = lane*2;
            out[(size_t)n*HID_ + c]     = 0.25f*acc.x + bias[c];
            out[(size_t)n*HID_ + c + 1] = 0.25f*acc.y + bias[c+1];
        }
    }
}

// BN stats: sum and sumsq per feature
__global__ void k_stats(const float* __restrict__ C, int N, int D, float* __restrict__ stats){
    int t = threadIdx.x;
    int f = t % D;
    int rl = t / D;
    int rstep = 256/D;
    int rows_per = (N + gridDim.x - 1)/gridDim.x;
    int r0 = blockIdx.x*rows_per;
    int r1 = min(N, r0 + rows_per);
    float s = 0.f, s2 = 0.f;
    for (int r = r0 + rl; r < r1; r += rstep){
        float v = C[(size_t)r*D + f];
        s += v; s2 += v*v;
    }
    __shared__ float sm[256], sm2[256];
    sm[t] = s; sm2[t] = s2; __syncthreads();
    for (int off = 128; off >= D; off >>= 1){
        if (t < off && t + off < 256){ sm[t] += sm[t+off]; sm2[t] += sm2[t+off]; }
        __syncthreads();
    }
    if (t < D){ atomicAdd(&stats[f], sm[t]); atomicAdd(&stats[128 + f], sm2[t]); }
}

__global__ void k_bnapply(const float* __restrict__ C, int N, int D,
                          const float* __restrict__ stats, const float* __restrict__ g,
                          const float* __restrict__ b, float* __restrict__ A){
    int idx = blockIdx.x*blockDim.x + threadIdx.x;
    if (idx >= N*D) return;
    int f = idx % D;
    float invN = 1.f/(float)N;
    float mu = stats[f]*invN;
    float var = stats[128 + f]*invN - mu*mu;
    float sc = rsqrtf(var + 1e-5f)*g[f];
    float y = (C[idx] - mu)*sc + b[f];
    A[idx] = elu_(y);
}

// ---------------- pooling + fc ----------------
__global__ void k_gate(const float* __restrict__ A, int N, const float* __restrict__ gw,
                       const float* __restrict__ gb, const int* __restrict__ batch,
                       float* __restrict__ exg, float* __restrict__ deng){
    int n = blockIdx.x*blockDim.x + threadIdx.x;
    if (n >= N) return;
    const float4* xr = (const float4*)(A + (size_t)n*HID_);
    const float4* wr = (const float4*)gw;
    float s = 0.f;
    #pragma unroll
    for (int q = 0; q < 8; q++){
        float4 v = xr[q]; float4 w = wr[q];
        s += v.x*w.x + v.y*w.y + v.z*w.z + v.w*w.w;
    }
    float ex = expf(s + gb[0]);
    exg[n] = ex;
    atomicAdd(&deng[batch[n]], ex);
}

__global__ void k_pool(const float* __restrict__ A, int N, const float* __restrict__ exg,
                       const int* __restrict__ batch, float* __restrict__ pool){
    int idx = blockIdx.x*blockDim.x + threadIdx.x;
    if (idx >= N*HID_) return;
    int n = idx >> 5, c = idx & 31;
    atomicAdd(&pool[batch[n]*HID_ + c], exg[n]*A[idx]);
}

__global__ void k_final(const float* __restrict__ pool, const float* __restrict__ deng,
                        const float* __restrict__ fcW, const float* __restrict__ fcb,
                        float* __restrict__ out){
    int t = threadIdx.x;
    if (t >= NG_*2) return;
    int g = t >> 1, o = t & 1;
    float invd = 1.f/(deng[g] + 1e-16f);
    float s = 0.f;
    for (int c = 0; c < HID_; c++) s += pool[g*HID_ + c]*invd*fcW[c*2 + o];
    out[t] = s + fcb[o];
}

extern "C" void kernel_launch(void* const* d_in, const int* in_sizes, int n_in,
                              void* d_out, int out_size, void* d_ws, size_t ws_size,
                              hipStream_t stream){
    const float* x   = (const float*)d_in[0];
    const int*   src = (const int*)d_in[1];
    const int*   dst = (const int*)d_in[2];
    const float* ea  = (const float*)d_in[3];
    const int* batch = (const int*)d_in[4];
    const float *W1=(const float*)d_in[5],  *as1=(const float*)d_in[6],  *ad1=(const float*)d_in[7];
    const float *We1=(const float*)d_in[8], *ae1=(const float*)d_in[9],  *b1=(const float*)d_in[10];
    const float *W2=(const float*)d_in[11], *as2=(const float*)d_in[12], *ad2=(const float*)d_in[13];
    const float *We2=(const float*)d_in[14],*ae2=(const float*)d_in[15], *b2=(const float*)d_in[16];
    const float *W3=(const float*)d_in[17], *as3=(const float*)d_in[18], *ad3=(const float*)d_in[19];
    const float *We3=(const float*)d_in[20],*ae3=(const float*)d_in[21], *b3=(const float*)d_in[22];
    const float *g1=(const float*)d_in[23], *be1=(const float*)d_in[24];
    const float *g2=(const float*)d_in[25], *be2=(const float*)d_in[26];
    const float *g3=(const float*)d_in[27], *be3=(const float*)d_in[28];
    const float *gw=(const float*)d_in[29], *gb=(const float*)d_in[30];
    const float *fcW=(const float*)d_in[31],*fcb=(const float*)d_in[32];
    int N = in_sizes[0]/DH;
    int E = in_sizes[1];

    float* ws = (float*)d_ws;
    size_t off = 0;
    float* A = ws + off;    off += (size_t)N*DH;
    float* B = ws + off;    off += (size_t)N*DH;   // h
    float* C = ws + off;    off += (size_t)N*DH;   // pre-BN output
    float* exs = ws + off;  off += (size_t)E*4;
    float* asrc = ws + off; off += (size_t)N*4;
    float* adst = ws + off; off += (size_t)N*4;
    int* ints   = (int*)(ws + off);
    int* srcs   = ints;
    int* dsts   = ints + (size_t)E;
    int* perm   = ints + 2*(size_t)E;
    int* rowst  = ints + 3*(size_t)E;
    int* counts = rowst + (N + 1);
    int* cursor = counts + N;
    int* bsums  = cursor + N;   // 256
    off += 3*(size_t)E + (N + 1) + 2*(size_t)N + 256;
    off = (off + 3) & ~(size_t)3;
    float* colsum = ws + off;      // 16
    float* Ve     = colsum + 16;   // 192
    float* selfae = Ve + 192;      // 16 (12 used)
    float* stats  = selfae + 16;   // 3*256
    float* deng   = stats + 768;   // 64
    float* pool   = deng + 64;     // 2048
    float* exg    = pool + 2048;   // N
    off += 16 + 192 + 16 + 768 + 64 + 2048 + (size_t)N;
    float* aedge = nullptr;
    if ((off + (size_t)E*12)*sizeof(float) <= ws_size) aedge = ws + off;

    hipMemsetAsync(counts, 0, (size_t)(2*N + 256)*sizeof(int), stream);
    hipMemsetAsync(colsum, 0, (size_t)(16 + 192 + 16 + 768 + 64 + 2048)*sizeof(float), stream);

    const int tb = 256;
    int gE = (E + tb - 1)/tb;
    int nb = (N + 511)/512;
    k_hist<<<gE, tb, 0, stream>>>(dst, E, counts);
    k_scan1<<<nb, 512, 0, stream>>>(counts, N, rowst, bsums);
    k_scan2<<<1, 1, 0, stream>>>(bsums, nb);
    k_scan3<<<(N + tb - 1)/tb, tb, 0, stream>>>(rowst, bsums, N, E);
    k_scatter<<<gE, tb, 0, stream>>>(src, dst, E, rowst, cursor, srcs, dsts, perm);
    k_eamean<<<256, 256, 0, stream>>>(ea, E, colsum);
    k_ve<<<1, 256, 0, stream>>>(We1, ae1, We2, ae2, We3, ae3, Ve);
    k_selfae<<<1, 64, 0, stream>>>(colsum, Ve, 1.f/(float)E, selfae);
    if (aedge) k_aedge<<<gE, tb, 0, stream>>>(ea, perm, E, Ve, aedge);

    int gG = (N + 7)/8;
    int gA = (N + 3)/4;
    // layer 1 (concat)
    k_gemm<128><<<gG, 256, 0, stream>>>(x, W1, as1, ad1, B, asrc, adst, N);
    k_edge_ex<<<gE, tb, 0, stream>>>(srcs, dsts, E, asrc, adst, aedge, 0, ea, perm, Ve, exs);
    k_agg<1><<<gA, 256, 0, stream>>>(rowst, srcs, exs, B, asrc, adst, selfae, 0, b1, C, N);
    k_stats<<<128, 256, 0, stream>>>(C, N, DH, stats);
    k_bnapply<<<((size_t)N*DH + tb - 1)/tb, tb, 0, stream>>>(C, N, DH, stats, g1, be1, A);
    // layer 2 (mean)
    k_gemm<128><<<gG, 256, 0, stream>>>(A, W2, as2, ad2, B, asrc, adst, N);
    k_edge_ex<<<gE, tb, 0, stream>>>(srcs, dsts, E, asrc, adst, aedge, 1, ea, perm, Ve, exs);
    k_agg<0><<<gA, 256, 0, stream>>>(rowst, srcs, exs, B, asrc, adst, selfae, 1, b2, C, N);
    k_stats<<<128, 256, 0, stream>>>(C, N, HID_, stats + 256);
    k_bnapply<<<((size_t)N*HID_ + tb - 1)/tb, tb, 0, stream>>>(C, N, HID_, stats + 256, g2, be2, A);
    // layer 3 (mean)
    k_gemm<32><<<gG, 256, 0, stream>>>(A, W3, as3, ad3, B, asrc, adst, N);
    k_edge_ex<<<gE, tb, 0, stream>>>(srcs, dsts, E, asrc, adst, aedge, 2, ea, perm, Ve, exs);
    k_agg<0><<<gA, 256, 0, stream>>>(rowst, srcs, exs, B, asrc, adst, selfae, 2, b3, C, N);
    k_stats<<<128, 256, 0, stream>>>(C, N, HID_, stats + 512);
    k_bnapply<<<((size_t)N*HID_ + tb - 1)/tb, tb, 0, stream>>>(C, N, HID_, stats + 512, g3, be3, A);
    // pooling + fc
    k_gate<<<(N + tb - 1)/tb, tb, 0, stream>>>(A, N, gw, gb, batch, exg, deng);
    k_pool<<<((size_t)N*HID_ + tb - 1)/tb, tb, 0, stream>>>(A, N, exg, batch, pool);
    k_final<<<1, 128, 0, stream>>>(pool, deng, fcW, fcb, (float*)d_out);
}

// Round 2
// 847.532 us; speedup vs baseline: 1.3363x; 1.3363x over previous
//
#include <hip/hip_runtime.h>
#include <math.h>

#define DH 128      // HEADS*HID
#define HID_ 32
#define HEADS_ 4
#define EDIM_ 16
#define NG_ 64

__device__ __forceinline__ float lrelu(float v){ return v > 0.f ? v : 0.2f*v; }
__device__ __forceinline__ float elu_(float v){ return v > 0.f ? v : (expf(v)-1.f); }

// ---------------- CSR build ----------------
__global__ void k_hist(const int* __restrict__ dst, int E, int* __restrict__ counts){
    int e = blockIdx.x*blockDim.x + threadIdx.x;
    if (e < E) atomicAdd(&counts[dst[e]], 1);
}

__global__ void k_scan1(const int* __restrict__ counts, int N, int* __restrict__ rowst, int* __restrict__ bsums){
    __shared__ int s[512];
    int t = threadIdx.x; int i = blockIdx.x*512 + t;
    int v = (i < N) ? counts[i] : 0;
    s[t] = v; __syncthreads();
    for (int off = 1; off < 512; off <<= 1){
        int x = (t >= off) ? s[t-off] : 0;
        __syncthreads();
        s[t] += x;
        __syncthreads();
    }
    if (i < N) rowst[i] = s[t] - v;   // exclusive
    if (t == 511) bsums[blockIdx.x] = s[511];
}

__global__ void k_scan2(int* bsums, int nb){
    if (threadIdx.x == 0 && blockIdx.x == 0){
        int run = 0;
        for (int b = 0; b < nb; b++){ int v = bsums[b]; bsums[b] = run; run += v; }
    }
}

__global__ void k_scan3(int* rowst, const int* __restrict__ bsums, int N, int E){
    int i = blockIdx.x*blockDim.x + threadIdx.x;
    if (i < N) rowst[i] += bsums[i/512];
    if (i == 0) rowst[N] = E;
}

__global__ void k_scatter(const int* __restrict__ src, const int* __restrict__ dst, int E,
                          const int* __restrict__ rowst, int* __restrict__ cursor,
                          int* __restrict__ srcs, int* __restrict__ dsts, int* __restrict__ perm){
    int e = blockIdx.x*blockDim.x + threadIdx.x;
    if (e < E){
        int d = dst[e];
        int p = rowst[d] + atomicAdd(&cursor[d], 1);
        srcs[p] = src[e]; dsts[p] = d; perm[p] = e;
    }
}

// ---------------- small param precompute ----------------
__global__ void k_eamean(const float* __restrict__ ea, int E, float* __restrict__ colsum){
    int t = threadIdx.x; int col = t & 15; int rl = t >> 4;   // 16 rows x 16 cols
    float s = 0.f;
    for (long r = (long)blockIdx.x*16 + rl; r < E; r += (long)gridDim.x*16)
        s += ea[r*EDIM_ + col];
    __shared__ float sm[256];
    sm[t] = s; __syncthreads();
    for (int off = 128; off >= 16; off >>= 1){ if (t < off) sm[t] += sm[t+off]; __syncthreads(); }
    if (t < 16) atomicAdd(&colsum[t], sm[t]);
}

__global__ void k_ve(const float* __restrict__ We0, const float* __restrict__ ae0,
                     const float* __restrict__ We1, const float* __restrict__ ae1,
                     const float* __restrict__ We2, const float* __restrict__ ae2,
                     float* __restrict__ Ve){
    int idx = threadIdx.x;
    if (idx < 192){
        int l = idx/64, r = idx%64, k = r/4, h = r%4;
        const float* We = (l==0) ? We0 : (l==1) ? We1 : We2;
        const float* ae = (l==0) ? ae0 : (l==1) ? ae1 : ae2;
        float s = 0.f;
        for (int c = 0; c < HID_; c++) s += We[k*DH + h*HID_ + c] * ae[h*HID_ + c];
        Ve[idx] = s;
    }
}

__global__ void k_selfae(const float* __restrict__ colsum, const float* __restrict__ Ve,
                         float invE, float* __restrict__ selfae){
    int idx = threadIdx.x;
    if (idx < 12){
        int l = idx/4, h = idx%4; float s = 0.f;
        for (int k = 0; k < EDIM_; k++) s += colsum[k]*invE*Ve[l*64 + k*4 + h];
        selfae[idx] = s;
    }
}

// aedge in dst-sorted order, all 3 layers, one gather of edge_attr
__global__ void k_aedge(const float* __restrict__ ea, const int* __restrict__ perm, int E,
                        const float* __restrict__ Ve, float* __restrict__ aedge){
    __shared__ float vsm[192];
    if (threadIdx.x < 192) vsm[threadIdx.x] = Ve[threadIdx.x];
    __syncthreads();
    int i = blockIdx.x*blockDim.x + threadIdx.x;
    if (i >= E) return;
    int e = perm[i];
    const float4* p = (const float4*)(ea + (size_t)e*EDIM_);
    float v[16];
    #pragma unroll
    for (int q = 0; q < 4; q++){ float4 x = p[q]; v[q*4]=x.x; v[q*4+1]=x.y; v[q*4+2]=x.z; v[q*4+3]=x.w; }
    #pragma unroll
    for (int l = 0; l < 3; l++){
        float4 o; float* po = (float*)&o;
        #pragma unroll
        for (int h = 0; h < 4; h++){
            float s = 0.f;
            #pragma unroll
            for (int k = 0; k < EDIM_; k++) s += v[k]*vsm[l*64 + k*4 + h];
            po[h] = s;
        }
        *(float4*)(aedge + (size_t)i*12 + l*4) = o;
    }
}

// ---------------- per-layer kernels ----------------
// h = x @ W  (W: [K,128] row-major), fused a_src/a_dst epilogue
template<int K>
__global__ __launch_bounds__(256) void k_gemm(const float* __restrict__ x, const float* __restrict__ W,
                        const float* __restrict__ attS, const float* __restrict__ attD,
                        float* __restrict__ h, float* __restrict__ asrc, float* __restrict__ adst, int N){
    constexpr int KC = (K > 64) ? 64 : K;
    __shared__ float4 Ws[KC*32];      // [KC][128] floats
    __shared__ float  xs[8*K];
    int t = threadIdx.x;
    int nbase = blockIdx.x*8;
    const float4* Wg = (const float4*)W;
    // load 8 rows of x
    constexpr int XF4 = 8*K/4;
    const float4* xg = (const float4*)(x + (size_t)nbase*K);
    float4* xs4 = (float4*)xs;
    for (int i = t; i < XF4; i += 256){
        int row = i/(K/4);
        xs4[i] = (nbase + row < N) ? xg[i] : float4{0,0,0,0};
    }
    int r = t >> 5, cg = t & 31;
    float4 acc = {0,0,0,0};
    const float* xr = xs + r*K;
    for (int kc = 0; kc < K; kc += KC){
        for (int i = t; i < KC*32; i += 256) Ws[i] = Wg[kc*32 + i];
        __syncthreads();
        #pragma unroll 8
        for (int kk = 0; kk < KC; kk++){
            float xv = xr[kc + kk];
            float4 w = Ws[kk*32 + cg];
            acc.x += xv*w.x; acc.y += xv*w.y; acc.z += xv*w.z; acc.w += xv*w.w;
        }
        __syncthreads();
    }
    int n = nbase + r;
    if (n < N){
        *(float4*)(h + (size_t)n*DH + cg*4) = acc;
        int hd = cg >> 3, c0 = (cg & 7)*4;
        const float* as_ = attS + hd*HID_ + c0;
        const float* ad_ = attD + hd*HID_ + c0;
        float ps = acc.x*as_[0] + acc.y*as_[1] + acc.z*as_[2] + acc.w*as_[3];
        float pd = acc.x*ad_[0] + acc.y*ad_[1] + acc.z*ad_[2] + acc.w*ad_[3];
        ps += __shfl_xor(ps,1); ps += __shfl_xor(ps,2); ps += __shfl_xor(ps,4);
        pd += __shfl_xor(pd,1); pd += __shfl_xor(pd,2); pd += __shfl_xor(pd,4);
        if ((cg & 7) == 0){ asrc[n*4 + hd] = ps; adst[n*4 + hd] = pd; }
    }
}

// ex = exp(leakyrelu(asrc[src]+adst[dst]+aedge)) per sorted edge
__global__ void k_edge_ex(const int* __restrict__ srcs, const int* __restrict__ dsts, int E,
                          const float* __restrict__ asrc, const float* __restrict__ adst,
                          const float* __restrict__ aedge, int l,
                          const float* __restrict__ ea, const int* __restrict__ perm,
                          const float* __restrict__ Ve, float* __restrict__ exs){
    int i = blockIdx.x*blockDim.x + threadIdx.x;
    if (i >= E) return;
    int s = srcs[i], d = dsts[i];
    float4 av = *(const float4*)(asrc + (size_t)s*4);
    float4 dv = *(const float4*)(adst + (size_t)d*4);
    float4 ae4;
    if (aedge){
        ae4 = *(const float4*)(aedge + (size_t)i*12 + l*4);
    } else {
        int e = perm[i];
        const float4* p = (const float4*)(ea + (size_t)e*EDIM_);
        float v[16];
        #pragma unroll
        for (int q = 0; q < 4; q++){ float4 x = p[q]; v[q*4]=x.x; v[q*4+1]=x.y; v[q*4+2]=x.z; v[q*4+3]=x.w; }
        float o[4];
        #pragma unroll
        for (int h = 0; h < 4; h++){
            float su = 0.f;
            #pragma unroll
            for (int k = 0; k < EDIM_; k++) su += v[k]*Ve[l*64 + k*4 + h];
            o[h] = su;
        }
        ae4 = float4{o[0],o[1],o[2],o[3]};
    }
    float4 o;
    o.x = expf(lrelu(av.x + dv.x + ae4.x));
    o.y = expf(lrelu(av.y + dv.y + ae4.y));
    o.z = expf(lrelu(av.z + dv.z + ae4.z));
    o.w = expf(lrelu(av.w + dv.w + ae4.w));
    *(float4*)(exs + (size_t)i*4) = o;
}

// one wave per node: softmax denominator + weighted aggregation + bias (+head-mean)
template<int CONCAT>
__global__ __launch_bounds__(256) void k_agg(const int* __restrict__ rowst, const int* __restrict__ srcs,
                       const float* __restrict__ exs, const float* __restrict__ h,
                       const float* __restrict__ asrc, const float* __restrict__ adst,
                       const float* __restrict__ selfae, int l,
                       const float* __restrict__ bias, float* __restrict__ out, int N){
    int wv = threadIdx.x >> 6, lane = threadIdx.x & 63;
    int n = blockIdx.x*4 + wv;
    if (n >= N) return;
    int st = rowst[n], en = rowst[n+1];
    float4 dsum = {0,0,0,0};
    for (int i = st + lane; i < en; i += 64){
        float4 e4 = *(const float4*)(exs + (size_t)i*4);
        dsum.x += e4.x; dsum.y += e4.y; dsum.z += e4.z; dsum.w += e4.w;
    }
    #pragma unroll
    for (int m = 1; m < 64; m <<= 1){
        dsum.x += __shfl_xor(dsum.x, m);
        dsum.y += __shfl_xor(dsum.y, m);
        dsum.z += __shfl_xor(dsum.z, m);
        dsum.w += __shfl_xor(dsum.w, m);
    }
    float4 av = *(const float4*)(asrc + (size_t)n*4);
    float4 dv = *(const float4*)(adst + (size_t)n*4);
    float4 sa = *(const float4*)(selfae + l*4);
    float4 exself;
    exself.x = expf(lrelu(av.x + dv.x + sa.x));
    exself.y = expf(lrelu(av.y + dv.y + sa.y));
    exself.z = expf(lrelu(av.z + dv.z + sa.z));
    exself.w = expf(lrelu(av.w + dv.w + sa.w));
    float4 den = {dsum.x+exself.x, dsum.y+exself.y, dsum.z+exself.z, dsum.w+exself.w};
    int hd = lane >> 4;
    float dh  = hd==0 ? den.x    : hd==1 ? den.y    : hd==2 ? den.z    : den.w;
    float esh = hd==0 ? exself.x : hd==1 ? exself.y : hd==2 ? exself.z : exself.w;
    float invd = 1.f/dh;
    int f = lane*2;
    float2 acc = {0.f, 0.f};
    for (int i = st; i < en; i++){
        float4 e4 = *(const float4*)(exs + (size_t)i*4);
        float w = (hd==0 ? e4.x : hd==1 ? e4.y : hd==2 ? e4.z : e4.w)*invd;
        int s = srcs[i];
        float2 hv = *(const float2*)(h + (size_t)s*DH + f);
        acc.x += w*hv.x; acc.y += w*hv.y;
    }
    float2 hn = *(const float2*)(h + (size_t)n*DH + f);
    float wself = esh*invd;
    acc.x += wself*hn.x; acc.y += wself*hn.y;
    if (CONCAT){
        out[(size_t)n*DH + f]     = acc.x + bias[f];
        out[(size_t)n*DH + f + 1] = acc.y + bias[f+1];
    } else {
        acc.x += __shfl_xor(acc.x, 16); acc.y += __shfl_xor(acc.y, 16);
        acc.x += __shfl_xor(acc.x, 32); acc.y += __shfl_xor(acc.y, 32);
        if (lane < 16){
            int c = lane*2;
            out[(size_t)n*HID_ + c]     = 0.25f*acc.x + bias[c];
            out[(size_t)n*HID_ + c + 1] = 0.25f*acc.y + bias[c+1];
        }
    }
}

// BN stats: sum and sumsq per feature
__global__ void k_stats(const float* __restrict__ C, int N, int D, float* __restrict__ stats){
    int t = threadIdx.x;
    int f = t % D;
    int rl = t / D;
    int rstep = 256/D;
    int rows_per = (N + gridDim.x - 1)/gridDim.x;
    int r0 = blockIdx.x*rows_per;
    int r1 = min(N, r0 + rows_per);
    float s = 0.f, s2 = 0.f;
    for (int r = r0 + rl; r < r1; r += rstep){
        float v = C[(size_t)r*D + f];
        s += v; s2 += v*v;
    }
    __shared__ float sm[256], sm2[256];
    sm[t] = s; sm2[t] = s2; __syncthreads();
    for (int off = 128; off >= D; off >>= 1){
        if (t < off && t + off < 256){ sm[t] += sm[t+off]; sm2[t] += sm2[t+off]; }
        __syncthreads();
    }
    if (t < D){ atomicAdd(&stats[f], sm[t]); atomicAdd(&stats[128 + f], sm2[t]); }
}

__global__ void k_bnapply(const float* __restrict__ C, int N, int D,
                          const float* __restrict__ stats, const float* __restrict__ g,
                          const float* __restrict__ b, float* __restrict__ A){
    int idx = blockIdx.x*blockDim.x + threadIdx.x;
    if (idx >= N*D) return;
    int f = idx % D;
    float invN = 1.f/(float)N;
    float mu = stats[f]*invN;
    float var = stats[128 + f]*invN - mu*mu;
    float sc = rsqrtf(var + 1e-5f)*g[f];
    float y = (C[idx] - mu)*sc + b[f];
    A[idx] = elu_(y);
}

// ---------------- pooling + fc: one block per graph, zero global atomics ----------------
__global__ __launch_bounds__(256) void k_poolfc(const float* __restrict__ A, int N,
        const float* __restrict__ gw, const float* __restrict__ gb,
        const int* __restrict__ batch, float* __restrict__ exg,
        const float* __restrict__ fcW, const float* __restrict__ fcb,
        float* __restrict__ out){
    int g = blockIdx.x;
    int t = threadIdx.x;
    // binary search graph range [st, en) in sorted batch
    int lo = 0, hi = N;
    while (lo < hi){ int mid = (lo+hi) >> 1; if (batch[mid] < g) lo = mid+1; else hi = mid; }
    int st = lo;
    hi = N;
    while (lo < hi){ int mid = (lo+hi) >> 1; if (batch[mid] < g+1) lo = mid+1; else hi = mid; }
    int en = lo;

    __shared__ float gws[32];
    __shared__ float red[256];
    if (t < 32) gws[t] = gw[t];
    __syncthreads();

    // pass 1: gate logits + denominator
    float den = 0.f;
    for (int n = st + t; n < en; n += 256){
        const float4* xr = (const float4*)(A + (size_t)n*HID_);
        float s = 0.f;
        #pragma unroll
        for (int q = 0; q < 8; q++){
            float4 v = xr[q];
            s += v.x*gws[q*4] + v.y*gws[q*4+1] + v.z*gws[q*4+2] + v.w*gws[q*4+3];
        }
        float ex = expf(s + gb[0]);
        exg[n] = ex;
        den += ex;
    }
    red[t] = den; __syncthreads();
    for (int off = 128; off > 0; off >>= 1){
        if (t < off) red[t] += red[t+off];
        __syncthreads();
    }
    float invd = 1.f/(red[0] + 1e-16f);
    __syncthreads();   // red[0] consumed by all before reuse

    // pass 2: pooled[c] = sum exg[n]*A[n,c]  (thread t: feature t&31, row-group t>>5)
    int c = t & 31, rg = t >> 5;
    float acc = 0.f;
    for (int n = st + rg; n < en; n += 8)
        acc += exg[n]*A[(size_t)n*HID_ + c];
    red[t] = acc; __syncthreads();
    if (t < 128) red[t] += red[t+128];
    __syncthreads();
    if (t < 64) red[t] += red[t+64];
    __syncthreads();
    if (t < 32) red[t] += red[t+32];
    __syncthreads();
    // red[0..31] = pooled sums; FC to 2 outputs
    if (t < 2){
        float s = 0.f;
        for (int cc = 0; cc < 32; cc++) s += red[cc]*invd*fcW[cc*2 + t];
        out[g*2 + t] = s + fcb[t];
    }
}

extern "C" void kernel_launch(void* const* d_in, const int* in_sizes, int n_in,
                              void* d_out, int out_size, void* d_ws, size_t ws_size,
                              hipStream_t stream){
    const float* x   = (const float*)d_in[0];
    const int*   src = (const int*)d_in[1];
    const int*   dst = (const int*)d_in[2];
    const float* ea  = (const float*)d_in[3];
    const int* batch = (const int*)d_in[4];
    const float *W1=(const float*)d_in[5],  *as1=(const float*)d_in[6],  *ad1=(const float*)d_in[7];
    const float *We1=(const float*)d_in[8], *ae1=(const float*)d_in[9],  *b1=(const float*)d_in[10];
    const float *W2=(const float*)d_in[11], *as2=(const float*)d_in[12], *ad2=(const float*)d_in[13];
    const float *We2=(const float*)d_in[14],*ae2=(const float*)d_in[15], *b2=(const float*)d_in[16];
    const float *W3=(const float*)d_in[17], *as3=(const float*)d_in[18], *ad3=(const float*)d_in[19];
    const float *We3=(const float*)d_in[20],*ae3=(const float*)d_in[21], *b3=(const float*)d_in[22];
    const float *g1=(const float*)d_in[23], *be1=(const float*)d_in[24];
    const float *g2=(const float*)d_in[25], *be2=(const float*)d_in[26];
    const float *g3=(const float*)d_in[27], *be3=(const float*)d_in[28];
    const float *gw=(const float*)d_in[29], *gb=(const float*)d_in[30];
    const float *fcW=(const float*)d_in[31],*fcb=(const float*)d_in[32];
    int N = in_sizes[0]/DH;
    int E = in_sizes[1];

    float* ws = (float*)d_ws;
    size_t off = 0;
    float* A = ws + off;    off += (size_t)N*DH;
    float* B = ws + off;    off += (size_t)N*DH;   // h
    float* C = ws + off;    off += (size_t)N*DH;   // pre-BN output
    float* exs = ws + off;  off += (size_t)E*4;
    float* asrc = ws + off; off += (size_t)N*4;
    float* adst = ws + off; off += (size_t)N*4;
    int* ints   = (int*)(ws + off);
    int* srcs   = ints;
    int* dsts   = ints + (size_t)E;
    int* perm   = ints + 2*(size_t)E;
    int* rowst  = ints + 3*(size_t)E;
    int* counts = rowst + (N + 1);
    int* cursor = counts + N;
    int* bsums  = cursor + N;   // 256
    off += 3*(size_t)E + (N + 1) + 2*(size_t)N + 256;
    off = (off + 3) & ~(size_t)3;
    float* colsum = ws + off;      // 16
    float* Ve     = colsum + 16;   // 192
    float* selfae = Ve + 192;      // 16 (12 used)
    float* stats  = selfae + 16;   // 3*256
    float* exg    = stats + 768;   // N
    off += 16 + 192 + 16 + 768 + (size_t)N;
    float* aedge = nullptr;
    if ((off + (size_t)E*12)*sizeof(float) <= ws_size) aedge = ws + off;

    hipMemsetAsync(counts, 0, (size_t)(2*N + 256)*sizeof(int), stream);
    hipMemsetAsync(colsum, 0, (size_t)(16 + 192 + 16 + 768)*sizeof(float), stream);

    const int tb = 256;
    int gE = (E + tb - 1)/tb;
    int nb = (N + 511)/512;
    k_hist<<<gE, tb, 0, stream>>>(dst, E, counts);
    k_scan1<<<nb, 512, 0, stream>>>(counts, N, rowst, bsums);
    k_scan2<<<1, 1, 0, stream>>>(bsums, nb);
    k_scan3<<<(N + tb - 1)/tb, tb, 0, stream>>>(rowst, bsums, N, E);
    k_scatter<<<gE, tb, 0, stream>>>(src, dst, E, rowst, cursor, srcs, dsts, perm);
    k_eamean<<<256, 256, 0, stream>>>(ea, E, colsum);
    k_ve<<<1, 256, 0, stream>>>(We1, ae1, We2, ae2, We3, ae3, Ve);
    k_selfae<<<1, 64, 0, stream>>>(colsum, Ve, 1.f/(float)E, selfae);
    if (aedge) k_aedge<<<gE, tb, 0, stream>>>(ea, perm, E, Ve, aedge);

    int gG = (N + 7)/8;
    int gA = (N + 3)/4;
    // layer 1 (concat)
    k_gemm<128><<<gG, 256, 0, stream>>>(x, W1, as1, ad1, B, asrc, adst, N);
    k_edge_ex<<<gE, tb, 0, stream>>>(srcs, dsts, E, asrc, adst, aedge, 0, ea, perm, Ve, exs);
    k_agg<1><<<gA, 256, 0, stream>>>(rowst, srcs, exs, B, asrc, adst, selfae, 0, b1, C, N);
    k_stats<<<128, 256, 0, stream>>>(C, N, DH, stats);
    k_bnapply<<<((size_t)N*DH + tb - 1)/tb, tb, 0, stream>>>(C, N, DH, stats, g1, be1, A);
    // layer 2 (mean)
    k_gemm<128><<<gG, 256, 0, stream>>>(A, W2, as2, ad2, B, asrc, adst, N);
    k_edge_ex<<<gE, tb, 0, stream>>>(srcs, dsts, E, asrc, adst, aedge, 1, ea, perm, Ve, exs);
    k_agg<0><<<gA, 256, 0, stream>>>(rowst, srcs, exs, B, asrc, adst, selfae, 1, b2, C, N);
    k_stats<<<128, 256, 0, stream>>>(C, N, HID_, stats + 256);
    k_bnapply<<<((size_t)N*HID_ + tb - 1)/tb, tb, 0, stream>>>(C, N, HID_, stats + 256, g2, be2, A);
    // layer 3 (mean)
    k_gemm<32><<<gG, 256, 0, stream>>>(A, W3, as3, ad3, B, asrc, adst, N);
    k_edge_ex<<<gE, tb, 0, stream>>>(srcs, dsts, E, asrc, adst, aedge, 2, ea, perm, Ve, exs);
    k_agg<0><<<gA, 256, 0, stream>>>(rowst, srcs, exs, B, asrc, adst, selfae, 2, b3, C, N);
    k_stats<<<128, 256, 0, stream>>>(C, N, HID_, stats + 512);
    k_bnapply<<<((size_t)N*HID_ + tb - 1)/tb, tb, 0, stream>>>(C, N, HID_, stats + 512, g3, be3, A);
    // pooling + fc (one block per graph, no atomics)
    k_poolfc<<<NG_, 256, 0, stream>>>(A, N, gw, gb, batch, exg, fcW, fcb, (float*)d_out);
}

// Round 3
// 677.846 us; speedup vs baseline: 1.6708x; 1.2503x over previous
//
#include <hip/hip_runtime.h>
#include <math.h>

#define DH 128      // HEADS*HID
#define HID_ 32
#define HEADS_ 4
#define EDIM_ 16
#define NG_ 64

__device__ __forceinline__ float lrelu(float v){ return v > 0.f ? v : 0.2f*v; }
__device__ __forceinline__ float elu_(float v){ return v > 0.f ? v : (expf(v)-1.f); }

// ---------------- CSR build ----------------
__global__ void k_hist(const int* __restrict__ dst, int E, int* __restrict__ counts){
    int e = blockIdx.x*blockDim.x + threadIdx.x;
    if (e < E) atomicAdd(&counts[dst[e]], 1);
}

__global__ void k_scan1(const int* __restrict__ counts, int N, int* __restrict__ rowst, int* __restrict__ bsums){
    __shared__ int s[512];
    int t = threadIdx.x; int i = blockIdx.x*512 + t;
    int v = (i < N) ? counts[i] : 0;
    s[t] = v; __syncthreads();
    for (int off = 1; off < 512; off <<= 1){
        int x = (t >= off) ? s[t-off] : 0;
        __syncthreads();
        s[t] += x;
        __syncthreads();
    }
    if (i < N) rowst[i] = s[t] - v;   // exclusive
    if (t == 511) bsums[blockIdx.x] = s[511];
}

__global__ void k_scan2(int* bsums, int nb){
    if (threadIdx.x == 0 && blockIdx.x == 0){
        int run = 0;
        for (int b = 0; b < nb; b++){ int v = bsums[b]; bsums[b] = run; run += v; }
    }
}

__global__ void k_scan3(int* rowst, const int* __restrict__ bsums, int N, int E){
    int i = blockIdx.x*blockDim.x + threadIdx.x;
    if (i < N) rowst[i] += bsums[i/512];
    if (i == 0) rowst[N] = E;
}

__global__ void k_scatter(const int* __restrict__ src, const int* __restrict__ dst, int E,
                          const int* __restrict__ rowst, int* __restrict__ cursor,
                          int* __restrict__ srcs, int* __restrict__ perm){
    int e = blockIdx.x*blockDim.x + threadIdx.x;
    if (e < E){
        int d = dst[e];
        int p = rowst[d] + atomicAdd(&cursor[d], 1);
        srcs[p] = src[e]; perm[p] = e;
    }
}

// ---------------- small param precompute ----------------
__global__ void k_eamean(const float* __restrict__ ea, int E, float* __restrict__ colsum){
    int t = threadIdx.x; int col = t & 15; int rl = t >> 4;   // 16 rows x 16 cols
    float s = 0.f;
    for (long r = (long)blockIdx.x*16 + rl; r < E; r += (long)gridDim.x*16)
        s += ea[r*EDIM_ + col];
    __shared__ float sm[256];
    sm[t] = s; __syncthreads();
    for (int off = 128; off >= 16; off >>= 1){ if (t < off) sm[t] += sm[t+off]; __syncthreads(); }
    if (t < 16) atomicAdd(&colsum[t], sm[t]);
}

__global__ void k_ve(const float* __restrict__ We0, const float* __restrict__ ae0,
                     const float* __restrict__ We1, const float* __restrict__ ae1,
                     const float* __restrict__ We2, const float* __restrict__ ae2,
                     float* __restrict__ Ve){
    int idx = threadIdx.x;
    if (idx < 192){
        int l = idx/64, r = idx%64, k = r/4, h = r%4;
        const float* We = (l==0) ? We0 : (l==1) ? We1 : We2;
        const float* ae = (l==0) ? ae0 : (l==1) ? ae1 : ae2;
        float s = 0.f;
        for (int c = 0; c < HID_; c++) s += We[k*DH + h*HID_ + c] * ae[h*HID_ + c];
        Ve[idx] = s;
    }
}

__global__ void k_selfae(const float* __restrict__ colsum, const float* __restrict__ Ve,
                         float invE, float* __restrict__ selfae){
    int idx = threadIdx.x;
    if (idx < 12){
        int l = idx/4, h = idx%4; float s = 0.f;
        for (int k = 0; k < EDIM_; k++) s += colsum[k]*invE*Ve[l*64 + k*4 + h];
        selfae[idx] = s;
    }
}

// a_edge for one layer, dst-sorted order: aout[i,h] = ea[perm[i],:] . Ve[l][:,h]
__global__ void k_aedge1(const float* __restrict__ ea, const int* __restrict__ perm, int E,
                         const float* __restrict__ Ve, int l, float* __restrict__ aout){
    __shared__ float vsm[64];
    if (threadIdx.x < 64) vsm[threadIdx.x] = Ve[l*64 + threadIdx.x];
    __syncthreads();
    int i = blockIdx.x*blockDim.x + threadIdx.x;
    if (i >= E) return;
    int e = perm[i];
    const float4* p = (const float4*)(ea + (size_t)e*EDIM_);
    float v[16];
    #pragma unroll
    for (int q = 0; q < 4; q++){ float4 x = p[q]; v[q*4]=x.x; v[q*4+1]=x.y; v[q*4+2]=x.z; v[q*4+3]=x.w; }
    float o[4];
    #pragma unroll
    for (int h = 0; h < 4; h++){
        float s = 0.f;
        #pragma unroll
        for (int k = 0; k < EDIM_; k++) s += v[k]*vsm[k*4 + h];
        o[h] = s;
    }
    *(float4*)(aout + (size_t)i*4) = float4{o[0],o[1],o[2],o[3]};
}

// ---------------- per-layer kernels ----------------
// h = x @ W  (W: [K,128] row-major), fused a_src/a_dst epilogue
template<int K>
__global__ __launch_bounds__(256) void k_gemm(const float* __restrict__ x, const float* __restrict__ W,
                        const float* __restrict__ attS, const float* __restrict__ attD,
                        float* __restrict__ h, float* __restrict__ asrc, float* __restrict__ adst, int N){
    constexpr int KC = (K > 64) ? 64 : K;
    __shared__ float4 Ws[KC*32];      // [KC][128] floats
    __shared__ float  xs[8*K];
    int t = threadIdx.x;
    int nbase = blockIdx.x*8;
    const float4* Wg = (const float4*)W;
    constexpr int XF4 = 8*K/4;
    const float4* xg = (const float4*)(x + (size_t)nbase*K);
    float4* xs4 = (float4*)xs;
    for (int i = t; i < XF4; i += 256){
        int row = i/(K/4);
        xs4[i] = (nbase + row < N) ? xg[i] : float4{0,0,0,0};
    }
    int r = t >> 5, cg = t & 31;
    float4 acc = {0,0,0,0};
    const float* xr = xs + r*K;
    for (int kc = 0; kc < K; kc += KC){
        for (int i = t; i < KC*32; i += 256) Ws[i] = Wg[kc*32 + i];
        __syncthreads();
        #pragma unroll 8
        for (int kk = 0; kk < KC; kk++){
            float xv = xr[kc + kk];
            float4 w = Ws[kk*32 + cg];
            acc.x += xv*w.x; acc.y += xv*w.y; acc.z += xv*w.z; acc.w += xv*w.w;
        }
        __syncthreads();
    }
    int n = nbase + r;
    if (n < N){
        *(float4*)(h + (size_t)n*DH + cg*4) = acc;
        int hd = cg >> 3, c0 = (cg & 7)*4;
        const float* as_ = attS + hd*HID_ + c0;
        const float* ad_ = attD + hd*HID_ + c0;
        float ps = acc.x*as_[0] + acc.y*as_[1] + acc.z*as_[2] + acc.w*as_[3];
        float pd = acc.x*ad_[0] + acc.y*ad_[1] + acc.z*ad_[2] + acc.w*ad_[3];
        ps += __shfl_xor(ps,1); ps += __shfl_xor(ps,2); ps += __shfl_xor(ps,4);
        pd += __shfl_xor(pd,1); pd += __shfl_xor(pd,2); pd += __shfl_xor(pd,4);
        if ((cg & 7) == 0){ asrc[n*4 + hd] = ps; adst[n*4 + hd] = pd; }
    }
}

// Fused GAT edge phase, layers 1/2: one wave per node, single pass,
// unnormalized accumulation + deferred normalize. 2 edges in flight per wave.
template<int CONCAT>
__global__ __launch_bounds__(256) void k_aggL(const int* __restrict__ rowst, const int* __restrict__ srcs,
        const float* __restrict__ asrc, const float* __restrict__ adst, const float* __restrict__ aedge,
        const float* __restrict__ h, const float* __restrict__ selfae4,
        const float* __restrict__ bias, float* __restrict__ out, int N){
    int wv = threadIdx.x >> 6, lane = threadIdx.x & 63;
    int n = blockIdx.x*4 + wv;
    if (n >= N) return;
    int st = rowst[n], en = rowst[n+1];
    float4 dv = *(const float4*)(adst + (size_t)n*4);
    int eoff = lane >> 5;        // which of 2 concurrent edges
    int fl = lane & 31;          // feature quad index (32 quads = 128 floats)
    int hd = fl >> 3;            // head
    int f = fl*4;
    float4 acc = {0,0,0,0};
    float4 densum = {0,0,0,0};
    for (int base = st; base < en; base += 64){
        int rem = en - base;
        int sj = 0; float4 exj = {0,0,0,0};
        if (lane < rem){
            sj = srcs[base + lane];
            float4 av = *(const float4*)(asrc + (size_t)sj*4);
            float4 ae4 = *(const float4*)(aedge + (size_t)(base+lane)*4);
            exj.x = expf(lrelu(av.x + dv.x + ae4.x));
            exj.y = expf(lrelu(av.y + dv.y + ae4.y));
            exj.z = expf(lrelu(av.z + dv.z + ae4.z));
            exj.w = expf(lrelu(av.w + dv.w + ae4.w));
        }
        densum.x += exj.x; densum.y += exj.y; densum.z += exj.z; densum.w += exj.w;
        int m = min(64, rem);
        for (int j = 0; j < m; j += 2){
            int jj = j + eoff;
            int s = __shfl(sj, jj);
            float w0 = __shfl(exj.x, jj), w1 = __shfl(exj.y, jj);
            float w2 = __shfl(exj.z, jj), w3v = __shfl(exj.w, jj);
            float w = hd==0 ? w0 : hd==1 ? w1 : hd==2 ? w2 : w3v;
            if (jj >= m) w = 0.f;
            float4 hv = *(const float4*)(h + (size_t)s*DH + f);
            acc.x += w*hv.x; acc.y += w*hv.y; acc.z += w*hv.z; acc.w += w*hv.w;
        }
    }
    #pragma unroll
    for (int msk = 1; msk < 64; msk <<= 1){
        densum.x += __shfl_xor(densum.x, msk);
        densum.y += __shfl_xor(densum.y, msk);
        densum.z += __shfl_xor(densum.z, msk);
        densum.w += __shfl_xor(densum.w, msk);
    }
    // combine the two edge-halves
    acc.x += __shfl_xor(acc.x, 32); acc.y += __shfl_xor(acc.y, 32);
    acc.z += __shfl_xor(acc.z, 32); acc.w += __shfl_xor(acc.w, 32);
    // self loop + normalize
    float4 av = *(const float4*)(asrc + (size_t)n*4);
    float4 sa = *(const float4*)selfae4;
    float4 exself;
    exself.x = expf(lrelu(av.x + dv.x + sa.x));
    exself.y = expf(lrelu(av.y + dv.y + sa.y));
    exself.z = expf(lrelu(av.z + dv.z + sa.z));
    exself.w = expf(lrelu(av.w + dv.w + sa.w));
    float es = hd==0 ? exself.x : hd==1 ? exself.y : hd==2 ? exself.z : exself.w;
    float dh4[4] = {densum.x + exself.x + 1e-16f, densum.y + exself.y + 1e-16f,
                    densum.z + exself.z + 1e-16f, densum.w + exself.w + 1e-16f};
    float invd = 1.f/dh4[hd];
    float4 hn = *(const float4*)(h + (size_t)n*DH + f);
    acc.x = (acc.x + es*hn.x)*invd; acc.y = (acc.y + es*hn.y)*invd;
    acc.z = (acc.z + es*hn.z)*invd; acc.w = (acc.w + es*hn.w)*invd;
    if (CONCAT){
        if (eoff == 0){
            const float* b4 = bias + f;
            float4 o = {acc.x + b4[0], acc.y + b4[1], acc.z + b4[2], acc.w + b4[3]};
            *(float4*)(out + (size_t)n*DH + f) = o;
        }
    } else {
        acc.x += __shfl_xor(acc.x, 8);  acc.y += __shfl_xor(acc.y, 8);
        acc.z += __shfl_xor(acc.z, 8);  acc.w += __shfl_xor(acc.w, 8);
        acc.x += __shfl_xor(acc.x, 16); acc.y += __shfl_xor(acc.y, 16);
        acc.z += __shfl_xor(acc.z, 16); acc.w += __shfl_xor(acc.w, 16);
        if (lane < 8){
            const float* b4 = bias + lane*4;
            float4 o = {0.25f*acc.x + b4[0], 0.25f*acc.y + b4[1],
                        0.25f*acc.z + b4[2], 0.25f*acc.w + b4[3]};
            *(float4*)(out + (size_t)n*HID_ + lane*4) = o;
        }
    }
}

// Layer 3: aggregate in A-space ([N,32], 128B rows) then apply W3 per node.
__global__ __launch_bounds__(256) void k_agg3(const int* __restrict__ rowst, const int* __restrict__ srcs,
        const float* __restrict__ asrc, const float* __restrict__ adst, const float* __restrict__ aedge,
        const float* __restrict__ A, const float* __restrict__ W3,
        const float* __restrict__ selfae4, const float* __restrict__ bias,
        float* __restrict__ out, int N){
    __shared__ float w3s[32*DH];     // 16 KB
    __shared__ float aggs[4][DH];    // per-wave normalized agg [head][k]
    int t = threadIdx.x;
    for (int i = t; i < 32*DH/4; i += 256) ((float4*)w3s)[i] = ((const float4*)W3)[i];
    __syncthreads();
    int wv = t >> 6, lane = t & 63;
    int n = blockIdx.x*4 + wv;
    bool active = n < N;
    int k = lane & 31, eoff = lane >> 5;
    float4 acc = {0,0,0,0};          // agg per head for feature k
    float4 densum = {0,0,0,0};
    int st = 0, en = 0;
    float4 dv = {0,0,0,0};
    if (active){
        st = rowst[n]; en = rowst[n+1];
        dv = *(const float4*)(adst + (size_t)n*4);
    }
    for (int base = st; base < en; base += 64){
        int rem = en - base;
        int sj = 0; float4 exj = {0,0,0,0};
        if (lane < rem){
            sj = srcs[base + lane];
            float4 av = *(const float4*)(asrc + (size_t)sj*4);
            float4 ae4 = *(const float4*)(aedge + (size_t)(base+lane)*4);
            exj.x = expf(lrelu(av.x + dv.x + ae4.x));
            exj.y = expf(lrelu(av.y + dv.y + ae4.y));
            exj.z = expf(lrelu(av.z + dv.z + ae4.z));
            exj.w = expf(lrelu(av.w + dv.w + ae4.w));
        }
        densum.x += exj.x; densum.y += exj.y; densum.z += exj.z; densum.w += exj.w;
        int m = min(64, rem);
        for (int j = 0; j < m; j += 2){
            int jj = j + eoff;
            int s = __shfl(sj, jj);
            float w0 = __shfl(exj.x, jj), w1 = __shfl(exj.y, jj);
            float w2 = __shfl(exj.z, jj), w3v = __shfl(exj.w, jj);
            float a = (jj < m) ? A[(size_t)s*HID_ + k] : 0.f;
            acc.x += w0*a; acc.y += w1*a; acc.z += w2*a; acc.w += w3v*a;
        }
    }
    #pragma unroll
    for (int msk = 1; msk < 64; msk <<= 1){
        densum.x += __shfl_xor(densum.x, msk);
        densum.y += __shfl_xor(densum.y, msk);
        densum.z += __shfl_xor(densum.z, msk);
        densum.w += __shfl_xor(densum.w, msk);
    }
    acc.x += __shfl_xor(acc.x, 32); acc.y += __shfl_xor(acc.y, 32);
    acc.z += __shfl_xor(acc.z, 32); acc.w += __shfl_xor(acc.w, 32);
    if (active){
        float4 av = *(const float4*)(asrc + (size_t)n*4);
        float4 sa = *(const float4*)selfae4;
        float4 exself;
        exself.x = expf(lrelu(av.x + dv.x + sa.x));
        exself.y = expf(lrelu(av.y + dv.y + sa.y));
        exself.z = expf(lrelu(av.z + dv.z + sa.z));
        exself.w = expf(lrelu(av.w + dv.w + sa.w));
        float aself = A[(size_t)n*HID_ + k];
        acc.x = (acc.x + exself.x*aself)/(densum.x + exself.x + 1e-16f);
        acc.y = (acc.y + exself.y*aself)/(densum.y + exself.y + 1e-16f);
        acc.z = (acc.z + exself.z*aself)/(densum.z + exself.z + 1e-16f);
        acc.w = (acc.w + exself.w*aself)/(densum.w + exself.w + 1e-16f);
        if (eoff == 0){
            aggs[wv][k]      = acc.x;
            aggs[wv][32 + k] = acc.y;
            aggs[wv][64 + k] = acc.z;
            aggs[wv][96 + k] = acc.w;
        }
    }
    __syncthreads();
    if (active){
        int c = lane & 31;
        int h0 = (lane >> 5)*2;
        float s = 0.f;
        #pragma unroll
        for (int hh = 0; hh < 2; hh++){
            int hq = h0 + hh;
            const float* ag = &aggs[wv][hq*32];
            const float* wc = &w3s[hq*32 + c];
            #pragma unroll 8
            for (int kk = 0; kk < 32; kk++) s += ag[kk]*wc[kk*DH];
        }
        s += __shfl_xor(s, 32);
        if (lane < 32) out[(size_t)n*HID_ + lane] = 0.25f*s + bias[lane];
    }
}

// collapse W3+att into [32,8]: cols 0-3 = a_src heads, 4-7 = a_dst heads
__global__ void k_w3att(const float* __restrict__ W3, const float* __restrict__ as3,
                        const float* __restrict__ ad3, float* __restrict__ Wsd){
    int t = threadIdx.x;  // 256
    int k = t >> 3, r = t & 7, h = r & 3;
    const float* att = (r >= 4) ? ad3 : as3;
    float s = 0.f;
    for (int c = 0; c < HID_; c++) s += W3[k*DH + h*HID_ + c]*att[h*HID_ + c];
    Wsd[k*8 + r] = s;
}

// asrc/adst for layer 3 from A [N,32] directly
__global__ void k_attn3(const float* __restrict__ A, int N, const float* __restrict__ Wsd,
                        float* __restrict__ asrc, float* __restrict__ adst){
    __shared__ float ws[256];
    ws[threadIdx.x] = Wsd[threadIdx.x & 255];
    __syncthreads();
    int n = blockIdx.x*blockDim.x + threadIdx.x;
    if (n >= N) return;
    float s[8] = {0,0,0,0,0,0,0,0};
    const float4* ar = (const float4*)(A + (size_t)n*HID_);
    #pragma unroll
    for (int kq = 0; kq < 8; kq++){
        float4 a = ar[kq];
        const float* w0 = &ws[kq*32];
        #pragma unroll
        for (int r = 0; r < 8; r++)
            s[r] += a.x*w0[r] + a.y*w0[8+r] + a.z*w0[16+r] + a.w*w0[24+r];
    }
    *(float4*)(asrc + (size_t)n*4) = float4{s[0],s[1],s[2],s[3]};
    *(float4*)(adst + (size_t)n*4) = float4{s[4],s[5],s[6],s[7]};
}

// BN stats: sum and sumsq per feature
__global__ void k_stats(const float* __restrict__ C, int N, int D, float* __restrict__ stats){
    int t = threadIdx.x;
    int f = t % D;
    int rl = t / D;
    int rstep = 256/D;
    int rows_per = (N + gridDim.x - 1)/gridDim.x;
    int r0 = blockIdx.x*rows_per;
    int r1 = min(N, r0 + rows_per);
    float s = 0.f, s2 = 0.f;
    for (int r = r0 + rl; r < r1; r += rstep){
        float v = C[(size_t)r*D + f];
        s += v; s2 += v*v;
    }
    __shared__ float sm[256], sm2[256];
    sm[t] = s; sm2[t] = s2; __syncthreads();
    for (int off = 128; off >= D; off >>= 1){
        if (t < off && t + off < 256){ sm[t] += sm[t+off]; sm2[t] += sm2[t+off]; }
        __syncthreads();
    }
    if (t < D){ atomicAdd(&stats[f], sm[t]); atomicAdd(&stats[128 + f], sm2[t]); }
}

__global__ void k_bnapply(const float* __restrict__ C, int N, int D,
                          const float* __restrict__ stats, const float* __restrict__ g,
                          const float* __restrict__ b, float* __restrict__ A){
    int idx = blockIdx.x*blockDim.x + threadIdx.x;
    if (idx >= N*D) return;
    int f = idx % D;
    float invN = 1.f/(float)N;
    float mu = stats[f]*invN;
    float var = stats[128 + f]*invN - mu*mu;
    float sc = rsqrtf(var + 1e-5f)*g[f];
    float y = (C[idx] - mu)*sc + b[f];
    A[idx] = elu_(y);
}

// ---------------- pooling + fc: one block per graph, zero global atomics ----------------
__global__ __launch_bounds__(256) void k_poolfc(const float* __restrict__ A, int N,
        const float* __restrict__ gw, const float* __restrict__ gb,
        const int* __restrict__ batch, float* __restrict__ exg,
        const float* __restrict__ fcW, const float* __restrict__ fcb,
        float* __restrict__ out){
    int g = blockIdx.x;
    int t = threadIdx.x;
    int lo = 0, hi = N;
    while (lo < hi){ int mid = (lo+hi) >> 1; if (batch[mid] < g) lo = mid+1; else hi = mid; }
    int st = lo;
    hi = N;
    while (lo < hi){ int mid = (lo+hi) >> 1; if (batch[mid] < g+1) lo = mid+1; else hi = mid; }
    int en = lo;

    __shared__ float gws[32];
    __shared__ float red[256];
    if (t < 32) gws[t] = gw[t];
    __syncthreads();

    float den = 0.f;
    for (int n = st + t; n < en; n += 256){
        const float4* xr = (const float4*)(A + (size_t)n*HID_);
        float s = 0.f;
        #pragma unroll
        for (int q = 0; q < 8; q++){
            float4 v = xr[q];
            s += v.x*gws[q*4] + v.y*gws[q*4+1] + v.z*gws[q*4+2] + v.w*gws[q*4+3];
        }
        float ex = expf(s + gb[0]);
        exg[n] = ex;
        den += ex;
    }
    red[t] = den; __syncthreads();
    for (int off = 128; off > 0; off >>= 1){
        if (t < off) red[t] += red[t+off];
        __syncthreads();
    }
    float invd = 1.f/(red[0] + 1e-16f);
    __syncthreads();

    int c = t & 31, rg = t >> 5;
    float acc = 0.f;
    for (int n = st + rg; n < en; n += 8)
        acc += exg[n]*A[(size_t)n*HID_ + c];
    red[t] = acc; __syncthreads();
    if (t < 128) red[t] += red[t+128];
    __syncthreads();
    if (t < 64) red[t] += red[t+64];
    __syncthreads();
    if (t < 32) red[t] += red[t+32];
    __syncthreads();
    if (t < 2){
        float s = 0.f;
        for (int cc = 0; cc < 32; cc++) s += red[cc]*invd*fcW[cc*2 + t];
        out[g*2 + t] = s + fcb[t];
    }
}

extern "C" void kernel_launch(void* const* d_in, const int* in_sizes, int n_in,
                              void* d_out, int out_size, void* d_ws, size_t ws_size,
                              hipStream_t stream){
    const float* x   = (const float*)d_in[0];
    const int*   src = (const int*)d_in[1];
    const int*   dst = (const int*)d_in[2];
    const float* ea  = (const float*)d_in[3];
    const int* batch = (const int*)d_in[4];
    const float *W1=(const float*)d_in[5],  *as1=(const float*)d_in[6],  *ad1=(const float*)d_in[7];
    const float *We1=(const float*)d_in[8], *ae1=(const float*)d_in[9],  *b1=(const float*)d_in[10];
    const float *W2=(const float*)d_in[11], *as2=(const float*)d_in[12], *ad2=(const float*)d_in[13];
    const float *We2=(const float*)d_in[14],*ae2=(const float*)d_in[15], *b2=(const float*)d_in[16];
    const float *W3=(const float*)d_in[17], *as3=(const float*)d_in[18], *ad3=(const float*)d_in[19];
    const float *We3=(const float*)d_in[20],*ae3=(const float*)d_in[21], *b3=(const float*)d_in[22];
    const float *g1=(const float*)d_in[23], *be1=(const float*)d_in[24];
    const float *g2=(const float*)d_in[25], *be2=(const float*)d_in[26];
    const float *g3=(const float*)d_in[27], *be3=(const float*)d_in[28];
    const float *gw=(const float*)d_in[29], *gb=(const float*)d_in[30];
    const float *fcW=(const float*)d_in[31],*fcb=(const float*)d_in[32];
    int N = in_sizes[0]/DH;
    int E = in_sizes[1];

    float* ws = (float*)d_ws;
    size_t off = 0;
    float* A = ws + off;    off += (size_t)N*DH;
    float* B = ws + off;    off += (size_t)N*DH;   // h
    float* C = ws + off;    off += (size_t)N*DH;   // pre-BN output
    float* asrc = ws + off; off += (size_t)N*4;
    float* adst = ws + off; off += (size_t)N*4;
    int* ints   = (int*)(ws + off);
    int* srcs   = ints;
    int* perm   = ints + (size_t)E;
    int* rowst  = ints + 2*(size_t)E;
    int* counts = rowst + (N + 1);
    int* cursor = counts + N;
    int* bsums  = cursor + N;   // 256
    off += 2*(size_t)E + (N + 1) + 2*(size_t)N + 256;
    off = (off + 3) & ~(size_t)3;
    float* colsum = ws + off;      // 16
    float* Ve     = colsum + 16;   // 192
    float* selfae = Ve + 192;      // 16 (12 used)
    float* stats  = selfae + 16;   // 3*256
    float* Wsd    = stats + 768;   // 256
    float* exg    = Wsd + 256;     // N
    off += 16 + 192 + 16 + 768 + 256 + (size_t)N;
    // aedge: prefer 3 resident arrays [E,4] each; fallback to 1 shared, recomputed per layer
    bool full = (off + (size_t)E*12)*sizeof(float) <= ws_size;
    float* ae0 = ws + off;
    float* ae1b = full ? ae0 + (size_t)E*4 : ae0;
    float* ae2b = full ? ae0 + (size_t)E*8 : ae0;

    hipMemsetAsync(counts, 0, (size_t)(2*N + 256)*sizeof(int), stream);
    hipMemsetAsync(colsum, 0, (size_t)(16 + 192 + 16 + 768)*sizeof(float), stream);

    const int tb = 256;
    int gE = (E + tb - 1)/tb;
    int nb = (N + 511)/512;
    k_hist<<<gE, tb, 0, stream>>>(dst, E, counts);
    k_scan1<<<nb, 512, 0, stream>>>(counts, N, rowst, bsums);
    k_scan2<<<1, 1, 0, stream>>>(bsums, nb);
    k_scan3<<<(N + tb - 1)/tb, tb, 0, stream>>>(rowst, bsums, N, E);
    k_scatter<<<gE, tb, 0, stream>>>(src, dst, E, rowst, cursor, srcs, perm);
    k_eamean<<<256, 256, 0, stream>>>(ea, E, colsum);
    k_ve<<<1, 256, 0, stream>>>(We1, ae1, We2, ae2, We3, ae3, Ve);
    k_selfae<<<1, 64, 0, stream>>>(colsum, Ve, 1.f/(float)E, selfae);
    k_w3att<<<1, 256, 0, stream>>>(W3, as3, ad3, Wsd);
    k_aedge1<<<gE, tb, 0, stream>>>(ea, perm, E, Ve, 0, ae0);
    if (full){
        k_aedge1<<<gE, tb, 0, stream>>>(ea, perm, E, Ve, 1, ae1b);
        k_aedge1<<<gE, tb, 0, stream>>>(ea, perm, E, Ve, 2, ae2b);
    }

    int gG = (N + 7)/8;
    int gA = (N + 3)/4;
    // layer 1 (concat)
    k_gemm<128><<<gG, 256, 0, stream>>>(x, W1, as1, ad1, B, asrc, adst, N);
    k_aggL<1><<<gA, 256, 0, stream>>>(rowst, srcs, asrc, adst, ae0, B, selfae + 0, b1, C, N);
    k_stats<<<128, 256, 0, stream>>>(C, N, DH, stats);
    k_bnapply<<<((size_t)N*DH + tb - 1)/tb, tb, 0, stream>>>(C, N, DH, stats, g1, be1, A);
    // layer 2 (mean)
    k_gemm<128><<<gG, 256, 0, stream>>>(A, W2, as2, ad2, B, asrc, adst, N);
    if (!full) k_aedge1<<<gE, tb, 0, stream>>>(ea, perm, E, Ve, 1, ae1b);
    k_aggL<0><<<gA, 256, 0, stream>>>(rowst, srcs, asrc, adst, ae1b, B, selfae + 4, b2, C, N);
    k_stats<<<128, 256, 0, stream>>>(C, N, HID_, stats + 256);
    k_bnapply<<<((size_t)N*HID_ + tb - 1)/tb, tb, 0, stream>>>(C, N, HID_, stats + 256, g2, be2, A);
    // layer 3 (mean, aggregated in A-space, no big GEMM)
    k_attn3<<<(N + tb - 1)/tb, tb, 0, stream>>>(A, N, Wsd, asrc, adst);
    if (!full) k_aedge1<<<gE, tb, 0, stream>>>(ea, perm, E, Ve, 2, ae2b);
    k_agg3<<<gA, 256, 0, stream>>>(rowst, srcs, asrc, adst, ae2b, A, W3, selfae + 8, b3, C, N);
    k_stats<<<128, 256, 0, stream>>>(C, N, HID_, stats + 512);
    k_bnapply<<<((size_t)N*HID_ + tb - 1)/tb, tb, 0, stream>>>(C, N, HID_, stats + 512, g3, be3, A);
    // pooling + fc
    k_poolfc<<<NG_, 256, 0, stream>>>(A, N, gw, gb, batch, exg, fcW, fcb, (float*)d_out);
}

// Round 4
// 673.752 us; speedup vs baseline: 1.6810x; 1.0061x over previous
//
#include <hip/hip_runtime.h>
#include <math.h>

#define DH 128      // HEADS*HID
#define HID_ 32
#define HEADS_ 4
#define EDIM_ 16
#define NG_ 64

__device__ __forceinline__ float lrelu(float v){ return v > 0.f ? v : 0.2f*v; }
__device__ __forceinline__ float elu_(float v){ return v > 0.f ? v : (__expf(v)-1.f); }

// ---------------- CSR build ----------------
__global__ void k_hist(const int* __restrict__ dst, int E, int* __restrict__ counts){
    int e = blockIdx.x*blockDim.x + threadIdx.x;
    if (e < E) atomicAdd(&counts[dst[e]], 1);
}

__global__ void k_scan1(const int* __restrict__ counts, int N, int* __restrict__ rowst, int* __restrict__ bsums){
    __shared__ int s[512];
    int t = threadIdx.x; int i = blockIdx.x*512 + t;
    int v = (i < N) ? counts[i] : 0;
    s[t] = v; __syncthreads();
    for (int off = 1; off < 512; off <<= 1){
        int x = (t >= off) ? s[t-off] : 0;
        __syncthreads();
        s[t] += x;
        __syncthreads();
    }
    if (i < N) rowst[i] = s[t] - v;   // exclusive
    if (t == 511) bsums[blockIdx.x] = s[511];
}

__global__ void k_scan2(int* bsums, int nb){
    if (threadIdx.x == 0 && blockIdx.x == 0){
        int run = 0;
        for (int b = 0; b < nb; b++){ int v = bsums[b]; bsums[b] = run; run += v; }
    }
}

__global__ void k_scan3(int* rowst, const int* __restrict__ bsums, int N, int E){
    int i = blockIdx.x*blockDim.x + threadIdx.x;
    if (i < N) rowst[i] += bsums[i/512];
    if (i == 0) rowst[N] = E;
}

// scatter edges to dst-sorted CSR; FUSE_AE: also compute a_edge for 3 layers
// (ea read coalesced in original order, results scatter-written 16B each)
template<int FUSE_AE>
__global__ void k_scatter(const int* __restrict__ src, const int* __restrict__ dst, int E,
                          const int* __restrict__ rowst, int* __restrict__ cursor,
                          const float* __restrict__ ea, const float* __restrict__ Ve,
                          int* __restrict__ srcs, int* __restrict__ perm,
                          float* __restrict__ ae0, float* __restrict__ ae1,
                          float* __restrict__ ae2){
    __shared__ float vsm[192];
    if (FUSE_AE && threadIdx.x < 192) vsm[threadIdx.x] = Ve[threadIdx.x];
    if (FUSE_AE) __syncthreads();
    int e = blockIdx.x*blockDim.x + threadIdx.x;
    if (e >= E) return;
    int d = dst[e];
    int p = rowst[d] + atomicAdd(&cursor[d], 1);
    srcs[p] = src[e];
    if (!FUSE_AE){ perm[p] = e; return; }
    const float4* pr = (const float4*)(ea + (size_t)e*EDIM_);
    float v[16];
    #pragma unroll
    for (int q = 0; q < 4; q++){ float4 x = pr[q]; v[q*4]=x.x; v[q*4+1]=x.y; v[q*4+2]=x.z; v[q*4+3]=x.w; }
    #pragma unroll
    for (int l = 0; l < 3; l++){
        float o[4];
        #pragma unroll
        for (int h = 0; h < 4; h++){
            float s = 0.f;
            #pragma unroll
            for (int k = 0; k < EDIM_; k++) s += v[k]*vsm[l*64 + k*4 + h];
            o[h] = s;
        }
        float* dstp = (l==0) ? ae0 : (l==1) ? ae1 : ae2;
        *(float4*)(dstp + (size_t)p*4) = float4{o[0],o[1],o[2],o[3]};
    }
}

// ---------------- small param precompute ----------------
// vectorized column sum of ea [E,16]
__global__ void k_eamean(const float* __restrict__ ea, int E, float* __restrict__ colsum){
    int t = threadIdx.x;
    size_t total = (size_t)E*4;          // float4 count
    float4 acc = {0,0,0,0};
    for (size_t i = (size_t)blockIdx.x*blockDim.x + t; i < total; i += (size_t)gridDim.x*blockDim.x){
        float4 v = ((const float4*)ea)[i];
        acc.x += v.x; acc.y += v.y; acc.z += v.z; acc.w += v.w;
    }
    __shared__ float4 sm[256];
    sm[t] = acc; __syncthreads();
    for (int off = 128; off >= 4; off >>= 1){
        if (t < off){
            sm[t].x += sm[t+off].x; sm[t].y += sm[t+off].y;
            sm[t].z += sm[t+off].z; sm[t].w += sm[t+off].w;
        }
        __syncthreads();
    }
    if (t < 4){
        float4 v = sm[t];
        atomicAdd(&colsum[t*4+0], v.x); atomicAdd(&colsum[t*4+1], v.y);
        atomicAdd(&colsum[t*4+2], v.z); atomicAdd(&colsum[t*4+3], v.w);
    }
}

__global__ void k_ve(const float* __restrict__ We0, const float* __restrict__ ae0,
                     const float* __restrict__ We1, const float* __restrict__ ae1,
                     const float* __restrict__ We2, const float* __restrict__ ae2,
                     float* __restrict__ Ve){
    int idx = threadIdx.x;
    if (idx < 192){
        int l = idx/64, r = idx%64, k = r/4, h = r%4;
        const float* We = (l==0) ? We0 : (l==1) ? We1 : We2;
        const float* ae = (l==0) ? ae0 : (l==1) ? ae1 : ae2;
        float s = 0.f;
        for (int c = 0; c < HID_; c++) s += We[k*DH + h*HID_ + c] * ae[h*HID_ + c];
        Ve[idx] = s;
    }
}

__global__ void k_selfae(const float* __restrict__ colsum, const float* __restrict__ Ve,
                         float invE, float* __restrict__ selfae){
    int idx = threadIdx.x;
    if (idx < 12){
        int l = idx/4, h = idx%4; float s = 0.f;
        for (int k = 0; k < EDIM_; k++) s += colsum[k]*invE*Ve[l*64 + k*4 + h];
        selfae[idx] = s;
    }
}

// fallback: a_edge for one layer via perm-gather
__global__ void k_aedge1(const float* __restrict__ ea, const int* __restrict__ perm, int E,
                         const float* __restrict__ Ve, int l, float* __restrict__ aout){
    __shared__ float vsm[64];
    if (threadIdx.x < 64) vsm[threadIdx.x] = Ve[l*64 + threadIdx.x];
    __syncthreads();
    int i = blockIdx.x*blockDim.x + threadIdx.x;
    if (i >= E) return;
    int e = perm[i];
    const float4* p = (const float4*)(ea + (size_t)e*EDIM_);
    float v[16];
    #pragma unroll
    for (int q = 0; q < 4; q++){ float4 x = p[q]; v[q*4]=x.x; v[q*4+1]=x.y; v[q*4+2]=x.z; v[q*4+3]=x.w; }
    float o[4];
    #pragma unroll
    for (int h = 0; h < 4; h++){
        float s = 0.f;
        #pragma unroll
        for (int k = 0; k < EDIM_; k++) s += v[k]*vsm[k*4 + h];
        o[h] = s;
    }
    *(float4*)(aout + (size_t)i*4) = float4{o[0],o[1],o[2],o[3]};
}

// ---------------- per-layer kernels ----------------
// h = x @ W  (W: [K,128] row-major), fused a_src/a_dst epilogue
template<int K>
__global__ __launch_bounds__(256) void k_gemm(const float* __restrict__ x, const float* __restrict__ W,
                        const float* __restrict__ attS, const float* __restrict__ attD,
                        float* __restrict__ h, float* __restrict__ asrc, float* __restrict__ adst, int N){
    constexpr int KC = (K > 64) ? 64 : K;
    __shared__ float4 Ws[KC*32];      // [KC][128] floats
    __shared__ float  xs[8*K];
    int t = threadIdx.x;
    int nbase = blockIdx.x*8;
    const float4* Wg = (const float4*)W;
    constexpr int XF4 = 8*K/4;
    const float4* xg = (const float4*)(x + (size_t)nbase*K);
    float4* xs4 = (float4*)xs;
    for (int i = t; i < XF4; i += 256){
        int row = i/(K/4);
        xs4[i] = (nbase + row < N) ? xg[i] : float4{0,0,0,0};
    }
    int r = t >> 5, cg = t & 31;
    float4 acc = {0,0,0,0};
    const float* xr = xs + r*K;
    for (int kc = 0; kc < K; kc += KC){
        for (int i = t; i < KC*32; i += 256) Ws[i] = Wg[kc*32 + i];
        __syncthreads();
        #pragma unroll 8
        for (int kk = 0; kk < KC; kk++){
            float xv = xr[kc + kk];
            float4 w = Ws[kk*32 + cg];
            acc.x += xv*w.x; acc.y += xv*w.y; acc.z += xv*w.z; acc.w += xv*w.w;
        }
        __syncthreads();
    }
    int n = nbase + r;
    if (n < N){
        *(float4*)(h + (size_t)n*DH + cg*4) = acc;
        int hd = cg >> 3, c0 = (cg & 7)*4;
        const float* as_ = attS + hd*HID_ + c0;
        const float* ad_ = attD + hd*HID_ + c0;
        float ps = acc.x*as_[0] + acc.y*as_[1] + acc.z*as_[2] + acc.w*as_[3];
        float pd = acc.x*ad_[0] + acc.y*ad_[1] + acc.z*ad_[2] + acc.w*ad_[3];
        ps += __shfl_xor(ps,1); ps += __shfl_xor(ps,2); ps += __shfl_xor(ps,4);
        pd += __shfl_xor(pd,1); pd += __shfl_xor(pd,2); pd += __shfl_xor(pd,4);
        if ((cg & 7) == 0){ asrc[n*4 + hd] = ps; adst[n*4 + hd] = pd; }
    }
}

// Fused GAT edge phase, layers 1/2: one wave per node, single pass,
// unnormalized accumulation + deferred normalize. 2 edges in flight per wave.
template<int CONCAT>
__global__ __launch_bounds__(256) void k_aggL(const int* __restrict__ rowst, const int* __restrict__ srcs,
        const float* __restrict__ asrc, const float* __restrict__ adst, const float* __restrict__ aedge,
        const float* __restrict__ h, const float* __restrict__ selfae4,
        const float* __restrict__ bias, float* __restrict__ out, int N){
    int wv = threadIdx.x >> 6, lane = threadIdx.x & 63;
    int n = blockIdx.x*4 + wv;
    if (n >= N) return;
    int st = rowst[n], en = rowst[n+1];
    float4 dv = *(const float4*)(adst + (size_t)n*4);
    int eoff = lane >> 5;        // which of 2 concurrent edges
    int fl = lane & 31;          // feature quad index (32 quads = 128 floats)
    int hd = fl >> 3;            // head
    int f = fl*4;
    float4 acc = {0,0,0,0};
    float4 densum = {0,0,0,0};
    for (int base = st; base < en; base += 64){
        int rem = en - base;
        int sj = 0; float4 exj = {0,0,0,0};
        if (lane < rem){
            sj = srcs[base + lane];
            float4 av = *(const float4*)(asrc + (size_t)sj*4);
            float4 ae4 = *(const float4*)(aedge + (size_t)(base+lane)*4);
            exj.x = __expf(lrelu(av.x + dv.x + ae4.x));
            exj.y = __expf(lrelu(av.y + dv.y + ae4.y));
            exj.z = __expf(lrelu(av.z + dv.z + ae4.z));
            exj.w = __expf(lrelu(av.w + dv.w + ae4.w));
        }
        densum.x += exj.x; densum.y += exj.y; densum.z += exj.z; densum.w += exj.w;
        int m = min(64, rem);
        for (int j = 0; j < m; j += 2){
            int jj = j + eoff;
            int s = __shfl(sj, jj);
            float w0 = __shfl(exj.x, jj), w1 = __shfl(exj.y, jj);
            float w2 = __shfl(exj.z, jj), w3v = __shfl(exj.w, jj);
            float w = hd==0 ? w0 : hd==1 ? w1 : hd==2 ? w2 : w3v;
            if (jj >= m) w = 0.f;
            float4 hv = *(const float4*)(h + (size_t)s*DH + f);
            acc.x += w*hv.x; acc.y += w*hv.y; acc.z += w*hv.z; acc.w += w*hv.w;
        }
    }
    #pragma unroll
    for (int msk = 1; msk < 64; msk <<= 1){
        densum.x += __shfl_xor(densum.x, msk);
        densum.y += __shfl_xor(densum.y, msk);
        densum.z += __shfl_xor(densum.z, msk);
        densum.w += __shfl_xor(densum.w, msk);
    }
    acc.x += __shfl_xor(acc.x, 32); acc.y += __shfl_xor(acc.y, 32);
    acc.z += __shfl_xor(acc.z, 32); acc.w += __shfl_xor(acc.w, 32);
    float4 av = *(const float4*)(asrc + (size_t)n*4);
    float4 sa = *(const float4*)selfae4;
    float4 exself;
    exself.x = __expf(lrelu(av.x + dv.x + sa.x));
    exself.y = __expf(lrelu(av.y + dv.y + sa.y));
    exself.z = __expf(lrelu(av.z + dv.z + sa.z));
    exself.w = __expf(lrelu(av.w + dv.w + sa.w));
    float es = hd==0 ? exself.x : hd==1 ? exself.y : hd==2 ? exself.z : exself.w;
    float dh4[4] = {densum.x + exself.x + 1e-16f, densum.y + exself.y + 1e-16f,
                    densum.z + exself.z + 1e-16f, densum.w + exself.w + 1e-16f};
    float invd = 1.f/dh4[hd];
    float4 hn = *(const float4*)(h + (size_t)n*DH + f);
    acc.x = (acc.x + es*hn.x)*invd; acc.y = (acc.y + es*hn.y)*invd;
    acc.z = (acc.z + es*hn.z)*invd; acc.w = (acc.w + es*hn.w)*invd;
    if (CONCAT){
        if (eoff == 0){
            const float* b4 = bias + f;
            float4 o = {acc.x + b4[0], acc.y + b4[1], acc.z + b4[2], acc.w + b4[3]};
            *(float4*)(out + (size_t)n*DH + f) = o;
        }
    } else {
        acc.x += __shfl_xor(acc.x, 8);  acc.y += __shfl_xor(acc.y, 8);
        acc.z += __shfl_xor(acc.z, 8);  acc.w += __shfl_xor(acc.w, 8);
        acc.x += __shfl_xor(acc.x, 16); acc.y += __shfl_xor(acc.y, 16);
        acc.z += __shfl_xor(acc.z, 16); acc.w += __shfl_xor(acc.w, 16);
        if (lane < 8){
            const float* b4 = bias + lane*4;
            float4 o = {0.25f*acc.x + b4[0], 0.25f*acc.y + b4[1],
                        0.25f*acc.z + b4[2], 0.25f*acc.w + b4[3]};
            *(float4*)(out + (size_t)n*HID_ + lane*4) = o;
        }
    }
}

// Layer 3: aggregate in A-space ([N,32], 128B rows), 8 edges in flight per wave,
// then apply W3 per node in LDS.
__global__ __launch_bounds__(256) void k_agg3(const int* __restrict__ rowst, const int* __restrict__ srcs,
        const float* __restrict__ asrc, const float* __restrict__ adst, const float* __restrict__ aedge,
        const float* __restrict__ A, const float* __restrict__ W3,
        const float* __restrict__ selfae4, const float* __restrict__ bias,
        float* __restrict__ out, int N){
    __shared__ float w3s[32*DH];     // 16 KB
    __shared__ float aggs[4][DH];    // per-wave normalized agg [head][k]
    int t = threadIdx.x;
    for (int i = t; i < 32*DH/4; i += 256) ((float4*)w3s)[i] = ((const float4*)W3)[i];
    __syncthreads();
    int wv = t >> 6, lane = t & 63;
    int n = blockIdx.x*4 + wv;
    bool active = n < N;
    int sub = lane >> 3;             // edge slot 0..7
    int fl = lane & 7;               // feature quad 0..7 (32 feats)
    float4 acc0 = {0,0,0,0}, acc1 = {0,0,0,0}, acc2 = {0,0,0,0}, acc3 = {0,0,0,0};
    float4 densum = {0,0,0,0};
    int st = 0, en = 0;
    float4 dv = {0,0,0,0};
    if (active){
        st = rowst[n]; en = rowst[n+1];
        dv = *(const float4*)(adst + (size_t)n*4);
    }
    for (int base = st; base < en; base += 64){
        int rem = en - base;
        int sj = 0; float4 exj = {0,0,0,0};
        if (lane < rem){
            sj = srcs[base + lane];
            float4 av = *(const float4*)(asrc + (size_t)sj*4);
            float4 ae4 = *(const float4*)(aedge + (size_t)(base+lane)*4);
            exj.x = __expf(lrelu(av.x + dv.x + ae4.x));
            exj.y = __expf(lrelu(av.y + dv.y + ae4.y));
            exj.z = __expf(lrelu(av.z + dv.z + ae4.z));
            exj.w = __expf(lrelu(av.w + dv.w + ae4.w));
        }
        densum.x += exj.x; densum.y += exj.y; densum.z += exj.z; densum.w += exj.w;
        int m = min(64, rem);
        for (int j = 0; j < m; j += 8){
            int jj = j + sub;        // lanes with jj >= rem contribute 0 (sj=0, exj=0)
            int s = __shfl(sj, jj);
            float w0 = __shfl(exj.x, jj), w1 = __shfl(exj.y, jj);
            float w2 = __shfl(exj.z, jj), w3v = __shfl(exj.w, jj);
            float4 a = *(const float4*)(A + (size_t)s*HID_ + fl*4);
            acc0.x += w0*a.x; acc0.y += w0*a.y; acc0.z += w0*a.z; acc0.w += w0*a.w;
            acc1.x += w1*a.x; acc1.y += w1*a.y; acc1.z += w1*a.z; acc1.w += w1*a.w;
            acc2.x += w2*a.x; acc2.y += w2*a.y; acc2.z += w2*a.z; acc2.w += w2*a.w;
            acc3.x += w3v*a.x; acc3.y += w3v*a.y; acc3.z += w3v*a.z; acc3.w += w3v*a.w;
        }
    }
    #pragma unroll
    for (int msk = 1; msk < 64; msk <<= 1){
        densum.x += __shfl_xor(densum.x, msk);
        densum.y += __shfl_xor(densum.y, msk);
        densum.z += __shfl_xor(densum.z, msk);
        densum.w += __shfl_xor(densum.w, msk);
    }
    #pragma unroll
    for (int msk = 8; msk < 64; msk <<= 1){
        acc0.x += __shfl_xor(acc0.x, msk); acc0.y += __shfl_xor(acc0.y, msk);
        acc0.z += __shfl_xor(acc0.z, msk); acc0.w += __shfl_xor(acc0.w, msk);
        acc1.x += __shfl_xor(acc1.x, msk); acc1.y += __shfl_xor(acc1.y, msk);
        acc1.z += __shfl_xor(acc1.z, msk); acc1.w += __shfl_xor(acc1.w, msk);
        acc2.x += __shfl_xor(acc2.x, msk); acc2.y += __shfl_xor(acc2.y, msk);
        acc2.z += __shfl_xor(acc2.z, msk); acc2.w += __shfl_xor(acc2.w, msk);
        acc3.x += __shfl_xor(acc3.x, msk); acc3.y += __shfl_xor(acc3.y, msk);
        acc3.z += __shfl_xor(acc3.z, msk); acc3.w += __shfl_xor(acc3.w, msk);
    }
    if (active){
        float4 av = *(const float4*)(asrc + (size_t)n*4);
        float4 sa = *(const float4*)selfae4;
        float4 exself;
        exself.x = __expf(lrelu(av.x + dv.x + sa.x));
        exself.y = __expf(lrelu(av.y + dv.y + sa.y));
        exself.z = __expf(lrelu(av.z + dv.z + sa.z));
        exself.w = __expf(lrelu(av.w + dv.w + sa.w));
        float4 aself = *(const float4*)(A + (size_t)n*HID_ + fl*4);
        float i0 = 1.f/(densum.x + exself.x + 1e-16f);
        float i1 = 1.f/(densum.y + exself.y + 1e-16f);
        float i2 = 1.f/(densum.z + exself.z + 1e-16f);
        float i3 = 1.f/(densum.w + exself.w + 1e-16f);
        acc0.x = (acc0.x + exself.x*aself.x)*i0; acc0.y = (acc0.y + exself.x*aself.y)*i0;
        acc0.z = (acc0.z + exself.x*aself.z)*i0; acc0.w = (acc0.w + exself.x*aself.w)*i0;
        acc1.x = (acc1.x + exself.y*aself.x)*i1; acc1.y = (acc1.y + exself.y*aself.y)*i1;
        acc1.z = (acc1.z + exself.y*aself.z)*i1; acc1.w = (acc1.w + exself.y*aself.w)*i1;
        acc2.x = (acc2.x + exself.z*aself.x)*i2; acc2.y = (acc2.y + exself.z*aself.y)*i2;
        acc2.z = (acc2.z + exself.z*aself.z)*i2; acc2.w = (acc2.w + exself.z*aself.w)*i2;
        acc3.x = (acc3.x + exself.w*aself.x)*i3; acc3.y = (acc3.y + exself.w*aself.y)*i3;
        acc3.z = (acc3.z + exself.w*aself.z)*i3; acc3.w = (acc3.w + exself.w*aself.w)*i3;
        if (sub == 0){
            *(float4*)&aggs[wv][ 0 + fl*4] = acc0;
            *(float4*)&aggs[wv][32 + fl*4] = acc1;
            *(float4*)&aggs[wv][64 + fl*4] = acc2;
            *(float4*)&aggs[wv][96 + fl*4] = acc3;
        }
    }
    __syncthreads();
    if (active){
        int c = lane & 31;
        int h0 = (lane >> 5)*2;
        float s = 0.f;
        #pragma unroll
        for (int hh = 0; hh < 2; hh++){
            int hq = h0 + hh;
            const float* ag = &aggs[wv][hq*32];
            const float* wc = &w3s[hq*32 + c];
            #pragma unroll 8
            for (int kk = 0; kk < 32; kk++) s += ag[kk]*wc[kk*DH];
        }
        s += __shfl_xor(s, 32);
        if (lane < 32) out[(size_t)n*HID_ + lane] = 0.25f*s + bias[lane];
    }
}

// collapse W3+att into [32,8]: cols 0-3 = a_src heads, 4-7 = a_dst heads
__global__ void k_w3att(const float* __restrict__ W3, const float* __restrict__ as3,
                        const float* __restrict__ ad3, float* __restrict__ Wsd){
    int t = threadIdx.x;  // 256
    int k = t >> 3, r = t & 7, h = r & 3;
    const float* att = (r >= 4) ? ad3 : as3;
    float s = 0.f;
    for (int c = 0; c < HID_; c++) s += W3[k*DH + h*HID_ + c]*att[h*HID_ + c];
    Wsd[k*8 + r] = s;
}

// asrc/adst for layer 3 from A [N,32] directly
__global__ void k_attn3(const float* __restrict__ A, int N, const float* __restrict__ Wsd,
                        float* __restrict__ asrc, float* __restrict__ adst){
    __shared__ float ws[256];
    ws[threadIdx.x] = Wsd[threadIdx.x & 255];
    __syncthreads();
    int n = blockIdx.x*blockDim.x + threadIdx.x;
    if (n >= N) return;
    float s[8] = {0,0,0,0,0,0,0,0};
    const float4* ar = (const float4*)(A + (size_t)n*HID_);
    #pragma unroll
    for (int kq = 0; kq < 8; kq++){
        float4 a = ar[kq];
        const float* w0 = &ws[kq*32];
        #pragma unroll
        for (int r = 0; r < 8; r++)
            s[r] += a.x*w0[r] + a.y*w0[8+r] + a.z*w0[16+r] + a.w*w0[24+r];
    }
    *(float4*)(asrc + (size_t)n*4) = float4{s[0],s[1],s[2],s[3]};
    *(float4*)(adst + (size_t)n*4) = float4{s[4],s[5],s[6],s[7]};
}

// BN stats: sum and sumsq per feature
__global__ void k_stats(const float* __restrict__ C, int N, int D, float* __restrict__ stats){
    int t = threadIdx.x;
    int f = t % D;
    int rl = t / D;
    int rstep = 256/D;
    int rows_per = (N + gridDim.x - 1)/gridDim.x;
    int r0 = blockIdx.x*rows_per;
    int r1 = min(N, r0 + rows_per);
    float s = 0.f, s2 = 0.f;
    for (int r = r0 + rl; r < r1; r += rstep){
        float v = C[(size_t)r*D + f];
        s += v; s2 += v*v;
    }
    __shared__ float sm[256], sm2[256];
    sm[t] = s; sm2[t] = s2; __syncthreads();
    for (int off = 128; off >= D; off >>= 1){
        if (t < off && t + off < 256){ sm[t] += sm[t+off]; sm2[t] += sm2[t+off]; }
        __syncthreads();
    }
    if (t < D){ atomicAdd(&stats[f], sm[t]); atomicAdd(&stats[128 + f], sm2[t]); }
}

__global__ void k_bnapply(const float* __restrict__ C, int N, int D,
                          const float* __restrict__ stats, const float* __restrict__ g,
                          const float* __restrict__ b, float* __restrict__ A){
    int idx = blockIdx.x*blockDim.x + threadIdx.x;
    if (idx >= N*D) return;
    int f = idx % D;
    float invN = 1.f/(float)N;
    float mu = stats[f]*invN;
    float var = stats[128 + f]*invN - mu*mu;
    float sc = rsqrtf(var + 1e-5f)*g[f];
    float y = (C[idx] - mu)*sc + b[f];
    A[idx] = elu_(y);
}

// ---------------- pooling + fc: one block per graph, zero global atomics ----------------
__global__ __launch_bounds__(256) void k_poolfc(const float* __restrict__ A, int N,
        const float* __restrict__ gw, const float* __restrict__ gb,
        const int* __restrict__ batch, float* __restrict__ exg,
        const float* __restrict__ fcW, const float* __restrict__ fcb,
        float* __restrict__ out){
    int g = blockIdx.x;
    int t = threadIdx.x;
    int lo = 0, hi = N;
    while (lo < hi){ int mid = (lo+hi) >> 1; if (batch[mid] < g) lo = mid+1; else hi = mid; }
    int st = lo;
    hi = N;
    while (lo < hi){ int mid = (lo+hi) >> 1; if (batch[mid] < g+1) lo = mid+1; else hi = mid; }
    int en = lo;

    __shared__ float gws[32];
    __shared__ float red[256];
    if (t < 32) gws[t] = gw[t];
    __syncthreads();

    float den = 0.f;
    for (int n = st + t; n < en; n += 256){
        const float4* xr = (const float4*)(A + (size_t)n*HID_);
        float s = 0.f;
        #pragma unroll
        for (int q = 0; q < 8; q++){
            float4 v = xr[q];
            s += v.x*gws[q*4] + v.y*gws[q*4+1] + v.z*gws[q*4+2] + v.w*gws[q*4+3];
        }
        float ex = __expf(s + gb[0]);
        exg[n] = ex;
        den += ex;
    }
    red[t] = den; __syncthreads();
    for (int off = 128; off > 0; off >>= 1){
        if (t < off) red[t] += red[t+off];
        __syncthreads();
    }
    float invd = 1.f/(red[0] + 1e-16f);
    __syncthreads();

    int c = t & 31, rg = t >> 5;
    float acc = 0.f;
    for (int n = st + rg; n < en; n += 8)
        acc += exg[n]*A[(size_t)n*HID_ + c];
    red[t] = acc; __syncthreads();
    if (t < 128) red[t] += red[t+128];
    __syncthreads();
    if (t < 64) red[t] += red[t+64];
    __syncthreads();
    if (t < 32) red[t] += red[t+32];
    __syncthreads();
    if (t < 2){
        float s = 0.f;
        for (int cc = 0; cc < 32; cc++) s += red[cc]*invd*fcW[cc*2 + t];
        out[g*2 + t] = s + fcb[t];
    }
}

extern "C" void kernel_launch(void* const* d_in, const int* in_sizes, int n_in,
                              void* d_out, int out_size, void* d_ws, size_t ws_size,
                              hipStream_t stream){
    const float* x   = (const float*)d_in[0];
    const int*   src = (const int*)d_in[1];
    const int*   dst = (const int*)d_in[2];
    const float* ea  = (const float*)d_in[3];
    const int* batch = (const int*)d_in[4];
    const float *W1=(const float*)d_in[5],  *as1=(const float*)d_in[6],  *ad1=(const float*)d_in[7];
    const float *We1=(const float*)d_in[8], *ae1=(const float*)d_in[9],  *b1=(const float*)d_in[10];
    const float *W2=(const float*)d_in[11], *as2=(const float*)d_in[12], *ad2=(const float*)d_in[13];
    const float *We2=(const float*)d_in[14],*ae2=(const float*)d_in[15], *b2=(const float*)d_in[16];
    const float *W3=(const float*)d_in[17], *as3=(const float*)d_in[18], *ad3=(const float*)d_in[19];
    const float *We3=(const float*)d_in[20],*ae3=(const float*)d_in[21], *b3=(const float*)d_in[22];
    const float *g1=(const float*)d_in[23], *be1=(const float*)d_in[24];
    const float *g2=(const float*)d_in[25], *be2=(const float*)d_in[26];
    const float *g3=(const float*)d_in[27], *be3=(const float*)d_in[28];
    const float *gw=(const float*)d_in[29], *gb=(const float*)d_in[30];
    const float *fcW=(const float*)d_in[31],*fcb=(const float*)d_in[32];
    int N = in_sizes[0]/DH;
    int E = in_sizes[1];

    float* ws = (float*)d_ws;
    size_t off = 0;
    float* A = ws + off;    off += (size_t)N*DH;
    float* B = ws + off;    off += (size_t)N*DH;   // h
    float* C = ws + off;    off += (size_t)N*DH;   // pre-BN output
    float* asrc = ws + off; off += (size_t)N*4;
    float* adst = ws + off; off += (size_t)N*4;
    int* ints   = (int*)(ws + off);
    int* srcs   = ints;
    int* perm   = ints + (size_t)E;
    int* rowst  = ints + 2*(size_t)E;
    int* counts = rowst + (N + 1);
    int* cursor = counts + N;
    int* bsums  = cursor + N;   // 256
    off += 2*(size_t)E + (N + 1) + 2*(size_t)N + 256;
    off = (off + 3) & ~(size_t)3;
    float* colsum = ws + off;      // 16
    float* Ve     = colsum + 16;   // 192
    float* selfae = Ve + 192;      // 16 (12 used)
    float* stats  = selfae + 16;   // 3*256
    float* Wsd    = stats + 768;   // 256
    float* exg    = Wsd + 256;     // N
    off += 16 + 192 + 16 + 768 + 256 + (size_t)N;
    // aedge: prefer 3 resident arrays [E,4] each; fallback to 1 shared, recomputed per layer
    bool full = (off + (size_t)E*12)*sizeof(float) <= ws_size;
    float* ae0 = ws + off;
    float* ae1b = full ? ae0 + (size_t)E*4 : ae0;
    float* ae2b = full ? ae0 + (size_t)E*8 : ae0;

    hipMemsetAsync(counts, 0, (size_t)(2*N + 256)*sizeof(int), stream);
    hipMemsetAsync(colsum, 0, (size_t)(16 + 192 + 16 + 768)*sizeof(float), stream);

    const int tb = 256;
    int gE = (E + tb - 1)/tb;
    int nb = (N + 511)/512;
    k_hist<<<gE, tb, 0, stream>>>(dst, E, counts);
    k_scan1<<<nb, 512, 0, stream>>>(counts, N, rowst, bsums);
    k_scan2<<<1, 1, 0, stream>>>(bsums, nb);
    k_scan3<<<(N + tb - 1)/tb, tb, 0, stream>>>(rowst, bsums, N, E);
    k_eamean<<<2048, 256, 0, stream>>>(ea, E, colsum);
    k_ve<<<1, 256, 0, stream>>>(We1, ae1, We2, ae2, We3, ae3, Ve);
    k_selfae<<<1, 64, 0, stream>>>(colsum, Ve, 1.f/(float)E, selfae);
    k_w3att<<<1, 256, 0, stream>>>(W3, as3, ad3, Wsd);
    if (full){
        k_scatter<1><<<gE, tb, 0, stream>>>(src, dst, E, rowst, cursor, ea, Ve,
                                            srcs, perm, ae0, ae1b, ae2b);
    } else {
        k_scatter<0><<<gE, tb, 0, stream>>>(src, dst, E, rowst, cursor, ea, Ve,
                                            srcs, perm, ae0, ae1b, ae2b);
        k_aedge1<<<gE, tb, 0, stream>>>(ea, perm, E, Ve, 0, ae0);
    }

    int gG = (N + 7)/8;
    int gA = (N + 3)/4;
    // layer 1 (concat)
    k_gemm<128><<<gG, 256, 0, stream>>>(x, W1, as1, ad1, B, asrc, adst, N);
    k_aggL<1><<<gA, 256, 0, stream>>>(rowst, srcs, asrc, adst, ae0, B, selfae + 0, b1, C, N);
    k_stats<<<128, 256, 0, stream>>>(C, N, DH, stats);
    k_bnapply<<<((size_t)N*DH + tb - 1)/tb, tb, 0, stream>>>(C, N, DH, stats, g1, be1, A);
    // layer 2 (mean)
    k_gemm<128><<<gG, 256, 0, stream>>>(A, W2, as2, ad2, B, asrc, adst, N);
    if (!full) k_aedge1<<<gE, tb, 0, stream>>>(ea, perm, E, Ve, 1, ae1b);
    k_aggL<0><<<gA, 256, 0, stream>>>(rowst, srcs, asrc, adst, ae1b, B, selfae + 4, b2, C, N);
    k_stats<<<128, 256, 0, stream>>>(C, N, HID_, stats + 256);
    k_bnapply<<<((size_t)N*HID_ + tb - 1)/tb, tb, 0, stream>>>(C, N, HID_, stats + 256, g2, be2, A);
    // layer 3 (mean, aggregated in A-space, no big GEMM)
    k_attn3<<<(N + tb - 1)/tb, tb, 0, stream>>>(A, N, Wsd, asrc, adst);
    if (!full) k_aedge1<<<gE, tb, 0, stream>>>(ea, perm, E, Ve, 2, ae2b);
    k_agg3<<<gA, 256, 0, stream>>>(rowst, srcs, asrc, adst, ae2b, A, W3, selfae + 8, b3, C, N);
    k_stats<<<128, 256, 0, stream>>>(C, N, HID_, stats + 512);
    k_bnapply<<<((size_t)N*HID_ + tb - 1)/tb, tb, 0, stream>>>(C, N, HID_, stats + 512, g3, be3, A);
    // pooling + fc
    k_poolfc<<<NG_, 256, 0, stream>>>(A, N, gw, gb, batch, exg, fcW, fcb, (float*)d_out);
}